// Round 15
// baseline (794.003 us; speedup 1.0000x reference)
//
#include <hip/hip_runtime.h>
#include <hip/hip_bf16.h>

// VQVAE forward, MI355X, fp32 encoder path (argmin stability).
// v15 = v14 + decoder restructure: k7s materializes d1raw into the dead h1p
// region (it already computes every value for stats); k9 becomes zero-LDS /
// zero-barrier, reading d1 rows directly through L1 with bn_d+relu fused at
// read (v14-k3 recipe). Encoder path untouched (argmin-stable).
// enc_b1/enc_b2/dec_b1 cancelled by training-mode BN -> unused.

#define EPSB 1e-5f

__device__ __forceinline__ float wredf(float v){
#pragma unroll
  for (int m = 32; m >= 1; m >>= 1) v += __shfl_xor(v, m, 64);
  return v;
}

__device__ __forceinline__ float fast_tanh(float x){
  float e = __expf(2.f * x);
  return fmaf(-2.f, __builtin_amdgcn_rcpf(e + 1.f), 1.f);
}

// ---------------- kP: weight transposes + P table + qsum=0 ------------------
__global__ __launch_bounds__(256) void kP(
    const float* __restrict__ w1, const float* __restrict__ w2,
    const float* __restrict__ dw2,
    const float* __restrict__ pqw, const float* __restrict__ pqb,
    const float* __restrict__ emb,
    float* __restrict__ wt1, float* __restrict__ wt2,
    float* __restrict__ wt9, float* __restrict__ misc)
{
  const int b = blockIdx.x, t = threadIdx.x;
  const int s = b*256 + t;                       // 0..16383
  { int tap = s >> 6, co = s & 63;               // wt2[tap=ci*16+ky*4+kx][co64]
    int ci = tap >> 4, ky = (tap >> 2) & 3, kx = tap & 3;
    wt2[s] = w2[((co*16 + ci)*4 + ky)*4 + kx]; }
  if (b == 0){
    for (int s2 = t; s2 < 768; s2 += 256){
      int tap = s2 >> 4, co = s2 & 15;           // wt1[tap][co16]
      int ci = tap >> 4, ky = (tap >> 2) & 3, kx = tap & 3;
      wt1[s2] = w1[((co*3 + ci)*4 + ky)*4 + kx];
      int ky9 = s2 / 192, rem = s2 - ky9*192;    // wt9[ky][ci][kx*3+co]
      int ci9 = rem / 12, r12 = rem - ci9*12;
      int kx9 = r12 / 3, co9 = r12 - kx9*3;
      wt9[s2] = dw2[((ci9*3 + co9)*4 + ky9)*4 + kx9];
    }
    if (t < 192){                                // P[i][ci] = postq(emb[i])
      int i = t >> 6, ci = t & 63;
      misc[200 + t] = fmaf(pqw[ci*2], emb[i*2],
                      fmaf(pqw[ci*2 + 1], emb[i*2 + 1], pqb[ci]));
    }
    if (t == 255) misc[192] = 0.f;               // qloss accumulator
  }
}

// ---------------- k6b: TT[i][ky][kx][oc] = sum_ci dec_w1 * P (parallel) -----
__global__ __launch_bounds__(64) void k6b_tt(
    const float* __restrict__ dw1, float* __restrict__ misc)
{
  const int e = blockIdx.x;                 // i*256 + (ky*4+kx)*16 + oc
  const int i = e >> 8, rem = e & 255;
  const int kykx = rem >> 4, oc = rem & 15;
  const int ky = kykx >> 2, kx = kykx & 3;
  const int l = threadIdx.x;                // ci (0..63)
  float v = dw1[((l*16 + oc)*4 + ky)*4 + kx] * misc[200 + i*64 + l];
  v = wredf(v);
  if (l == 0) misc[400 + i*260 + rem] = v;  // stride 260 pad (1040B, 16B-mult)
}

// ---------------- k1: conv1 3->16 s2 p1 -> parity-split h1p + stats ----------
// h1p[n][co16][yp][xp][128][128]; yp=oy&1, xp=ox&1.
__global__ __launch_bounds__(256) void k1_conv1(
    const float* __restrict__ x, const float* __restrict__ wt1,
    float* __restrict__ h1p, float* __restrict__ part1)
{
  __shared__ __align__(16) float xt[3*6*516];
  __shared__ float red[128];
  const int b = blockIdx.x, t = threadIdx.x;
  const int n = b >> 7, yt = b & 127;
  const int oy0 = yt << 1, iy0 = (oy0 << 1) - 1;
  // staging: 18 rows, 2 rows per pass; interior via float4, edges zeroed.
  const int rh = t >> 7, l128 = t & 127, c4 = l128 << 2;
#pragma unroll
  for (int rp = 0; rp < 9; rp++){
    int rIdx = (rp << 1) + rh;              // 0..17 = ci*6+rr
    int ci = rIdx / 6, rr = rIdx - ci*6;
    int iy = iy0 + rr;
    bool yok = (unsigned)iy < 512u;
    const float* xr = x + (((size_t)(n*3 + ci)) << 18) + ((size_t)(iy & 511) << 9);
    float* dst = &xt[rIdx*516];
    float4 v = make_float4(0.f, 0.f, 0.f, 0.f);
    if (yok) v = *(const float4*)&xr[c4];
    dst[c4 + 1] = v.x; dst[c4 + 2] = v.y; dst[c4 + 3] = v.z; dst[c4 + 4] = v.w;
    if (l128 == 0){ dst[0] = 0.f; dst[513] = 0.f; }
  }
  __syncthreads();
  const int w = t >> 6, l = t & 63;
  const int oyr = w & 1, xh = w >> 1;
  float acc[2][16];
#pragma unroll
  for (int j = 0; j < 2; j++)
#pragma unroll
    for (int q = 0; q < 16; q++) acc[j][q] = 0.f;

  for (int ci = 0; ci < 3; ci++){
    for (int ky = 0; ky < 4; ky++){
      const float* xrow = &xt[(ci*6 + (oyr << 1) + ky)*516];
      float v[2][4];
#pragma unroll
      for (int j = 0; j < 2; j++){
        int ox = (xh << 7) + (j << 6) + l;
        float2 p0 = *(const float2*)&xrow[2*ox];
        float2 p1 = *(const float2*)&xrow[2*ox + 2];
        v[j][0] = p0.x; v[j][1] = p0.y; v[j][2] = p1.x; v[j][3] = p1.y;
      }
      const float* wb = &wt1[((ci*4 + ky) << 6)];
#pragma unroll
      for (int kx = 0; kx < 4; kx++){
        const float* wp = wb + (kx << 4);        // uniform -> s_load
        float wv[16];
#pragma unroll
        for (int q = 0; q < 16; q++) wv[q] = wp[q];
#pragma unroll
        for (int j = 0; j < 2; j++)
#pragma unroll
          for (int q = 0; q < 16; q++) acc[j][q] = fmaf(v[j][kx], wv[q], acc[j][q]);
      }
    }
  }
  float s[16], ss[16];
#pragma unroll
  for (int q = 0; q < 16; q++){ s[q] = 0.f; ss[q] = 0.f; }
  const int xp = l & 1;
#pragma unroll
  for (int j = 0; j < 2; j++){
    int m = (xh << 6) + (j << 5) + (l >> 1);
#pragma unroll
    for (int q = 0; q < 16; q++){
      float vv = acc[j][q];
      h1p[((((size_t)(n*16 + q) << 1) + oyr) << 15) + ((size_t)xp << 14) + (yt << 7) + m] = vv;
      s[q] += vv; ss[q] += vv*vv;
    }
  }
#pragma unroll
  for (int q = 0; q < 16; q++){ s[q] = wredf(s[q]); ss[q] = wredf(ss[q]); }
  if (l == 0){
#pragma unroll
    for (int q = 0; q < 16; q++){ red[w*32 + q] = s[q]; red[w*32 + 16 + q] = ss[q]; }
  }
  __syncthreads();
  if (t < 32) part1[b*32 + t] = red[t] + red[32+t] + red[64+t] + red[96+t];
}

// ---------------- reduce partials -> scale/shift (BN) ------------------------
__global__ __launch_bounds__(256) void k_stats(
    const float* __restrict__ part, int nslots, int slotstride, int grouped,
    const float* __restrict__ g, const float* __restrict__ be,
    float* __restrict__ scale, float* __restrict__ shift, float Ninv)
{
  const int c = blockIdx.x, t = threadIdx.x;
  const int off = grouped ? ((c >> 4) << 5) : 0;
  const int ci = grouped ? (c & 15) : c;
  float S = 0.f, SS = 0.f;
  for (int q = t; q < nslots; q += 256){
    const float* pp = &part[(size_t)q * slotstride + off];
    S += pp[ci]; SS += pp[16 + ci];
  }
  S = wredf(S); SS = wredf(SS);
  __shared__ float sb[8];
  if ((t & 63) == 0){ sb[t >> 6] = S; sb[4 + (t >> 6)] = SS; }
  __syncthreads();
  if (t == 0){
    float Sv = sb[0]+sb[1]+sb[2]+sb[3], SSv = sb[4]+sb[5]+sb[6]+sb[7];
    float m = Sv * Ninv;
    float var = SSv * Ninv - m*m;
    float sc = g[c] * rsqrtf(var + EPSB);
    scale[c] = sc;
    shift[c] = be[c] - m * sc;
  }
}

// ---------------- k3: conv2 16->64 s2 p1 — direct-L1, zero staging ----------
__global__ __launch_bounds__(256) void k3_conv2(
    const float* __restrict__ h1p, const float* __restrict__ wt2,
    const float* __restrict__ misc, float* __restrict__ h2,
    float* __restrict__ part2)
{
  __shared__ float red[128];
  const int b = blockIdx.x, t = threadIdx.x;
  const int n = b >> 6, yt = b & 63;
  const int oy0 = yt << 1;
  const int w = __builtin_amdgcn_readfirstlane(t >> 6);  // co-group
  const int l = t & 63, oyr = l >> 5, lx = l & 31;
  float acc[4][16];
#pragma unroll
  for (int e = 0; e < 4; e++)
#pragma unroll
    for (int q = 0; q < 16; q++) acc[e][q] = 0.f;

  const int myk[4] = {oy0 + oyr - 1, oy0 + oyr, oy0 + oyr, oy0 + oyr + 1};
  const int ypk[4] = {1, 0, 1, 0};
  const int lxo = lx << 2;

  for (int g = 0; g < 16; g++){
    const float sc = misc[g], sh = misc[16 + g];         // uniform -> s_load
    const float* pg = h1p + (((size_t)(n*16 + g)) << 16);
#pragma unroll
    for (int ky = 0; ky < 4; ky++){
      const int m_y = myk[ky];
      const bool rv = (unsigned)m_y < 128u;
      const int myc = m_y & 127;
      const float scv = rv ? sc : 0.f, shv = rv ? sh : 0.f;
      const float* rb = pg + ((size_t)ypk[ky] << 15) + (myc << 7) + lxo;
      float4 R0 = *(const float4*)rb;              // xp0 m..m+3
      float4 R1 = *(const float4*)(rb + 16384);    // xp1 m..m+3
      float A0x = fmaxf(fmaf(R0.x, scv, shv), 0.f);
      float A0y = fmaxf(fmaf(R0.y, scv, shv), 0.f);
      float A0z = fmaxf(fmaf(R0.z, scv, shv), 0.f);
      float A0w = fmaxf(fmaf(R0.w, scv, shv), 0.f);
      float A1x = fmaxf(fmaf(R1.x, scv, shv), 0.f);
      float A1y = fmaxf(fmaf(R1.y, scv, shv), 0.f);
      float A1z = fmaxf(fmaf(R1.z, scv, shv), 0.f);
      float A1w = fmaxf(fmaf(R1.w, scv, shv), 0.f);
      float nx0 = __shfl_down(A0x, 1, 64);  if (lx == 31) nx0 = 0.f;
      float pv1 = __shfl_up(A1w, 1, 64);    if (lx == 0)  pv1 = 0.f;
      float act0[4] = {pv1, A1x, A1y, A1z};   // kx=0: xp1 m-1
      float act1[4] = {A0x, A0y, A0z, A0w};   // kx=1: xp0 m
      float act2[4] = {A1x, A1y, A1z, A1w};   // kx=2: xp1 m
      float act3[4] = {A0y, A0z, A0w, nx0};   // kx=3: xp0 m+1
      const float* wb = &wt2[(((g << 4) + (ky << 2)) << 6) + (w << 4)];
#pragma unroll
      for (int kx = 0; kx < 4; kx++){
        const float* wp = wb + (kx << 6);      // uniform -> s_load x16
        float wv[16];
#pragma unroll
        for (int q = 0; q < 16; q++) wv[q] = wp[q];
        const float* av = (kx == 0) ? act0 : (kx == 1) ? act1 : (kx == 2) ? act2 : act3;
#pragma unroll
        for (int e = 0; e < 4; e++)
#pragma unroll
          for (int q = 0; q < 16; q++)
            acc[e][q] = fmaf(av[e], wv[q], acc[e][q]);
      }
    }
  }
  const int oy = oy0 + oyr;
  float s[16], ss[16];
#pragma unroll
  for (int q = 0; q < 16; q++){ s[q] = 0.f; ss[q] = 0.f; }
#pragma unroll
  for (int e = 0; e < 4; e++)
#pragma unroll
    for (int q = 0; q < 16; q++){ float v = acc[e][q]; s[q] += v; ss[q] += v*v; }
#pragma unroll
  for (int q = 0; q < 16; q++){
    float4 o = make_float4(acc[0][q], acc[1][q], acc[2][q], acc[3][q]);
    *(float4*)&h2[(((size_t)(n*64) + (w << 4) + q) << 14) + (oy << 7) + (lx << 2)] = o;
  }
#pragma unroll
  for (int q = 0; q < 16; q++){ s[q] = wredf(s[q]); ss[q] = wredf(ss[q]); }
  if (l == 0){
#pragma unroll
    for (int q = 0; q < 16; q++){ red[w*32 + q] = s[q]; red[w*32 + 16 + q] = ss[q]; }
  }
  __syncthreads();
  if (t < 128) part2[b*128 + t] = red[t];
}

// ---------------- k5: preq(bn2+relu fused) + VQ argmin + qloss + idx ---------
__global__ __launch_bounds__(256) void k5_vq(
    const float* __restrict__ h2, const float* __restrict__ misc,
    const float* __restrict__ pw, const float* __restrict__ pb,
    const float* __restrict__ emb, unsigned char* __restrict__ idxb,
    float* __restrict__ qsum)
{
  __shared__ float eb[4];
  const int t = threadIdx.x;
  const int p0 = blockIdx.x*512 + (t << 1);
  const int n = p0 >> 14, pos = p0 & 16383;
  const float* hp = h2 + ((size_t)n << 20) + pos;
  float q0[2], q1[2];
  const float pb0 = pb[0], pb1 = pb[1];
#pragma unroll
  for (int j = 0; j < 2; j++){ q0[j] = pb0; q1[j] = pb1; }
  for (int c = 0; c < 64; c++){
    float2 v = *(const float2*)&hp[(size_t)c << 14];
    float sc = misc[32 + c], sh = misc[96 + c];   // uniform -> s_load
    float w0 = pw[c], w1 = pw[64 + c];            // uniform -> s_load
    float a0 = fmaxf(fmaf(v.x, sc, sh), 0.f);
    float a1 = fmaxf(fmaf(v.y, sc, sh), 0.f);
    q0[0] = fmaf(a0, w0, q0[0]); q1[0] = fmaf(a0, w1, q1[0]);
    q0[1] = fmaf(a1, w0, q0[1]); q1[1] = fmaf(a1, w1, q1[1]);
  }
  const float e00 = emb[0], e01 = emb[1], e10 = emb[2], e11 = emb[3],
              e20 = emb[4], e21 = emb[5];
  float esum = 0.f;
  unsigned char bi[2];
#pragma unroll
  for (int j = 0; j < 2; j++){
    float dx0 = q0[j]-e00, dy0 = q1[j]-e01;
    float dx1 = q0[j]-e10, dy1 = q1[j]-e11;
    float dx2 = q0[j]-e20, dy2 = q1[j]-e21;
    float d0 = dx0*dx0+dy0*dy0, d1 = dx1*dx1+dy1*dy1, d2 = dx2*dx2+dy2*dy2;
    int bj = 0; float db = d0;
    if (d1 < db){ db = d1; bj = 1; }
    if (d2 < db){ db = d2; bj = 2; }
    bi[j] = (unsigned char)bj; esum += db;
  }
  *(uchar2*)&idxb[p0] = make_uchar2(bi[0], bi[1]);
  float e = wredf(esum);
  if ((t & 63) == 0) eb[t >> 6] = e;
  __syncthreads();
  if (t == 0) atomicAdd(qsum, eb[0]+eb[1]+eb[2]+eb[3]);
}

// d1raw at (iy,ix): sum of <=4 TT entries via idx map (convT1 collapsed).
__device__ __forceinline__ void d1_accum(const unsigned char* __restrict__ ib,
    int iy, int ix, const float* __restrict__ tt, float* __restrict__ d)
{
  const int py = (iy + 1) & 1, px = (ix + 1) & 1;
#pragma unroll
  for (int kyi = 0; kyi < 2; kyi++){
    int ky = py + 2*kyi, jy = (iy + 1 - ky) >> 1;
    if ((unsigned)jy < 128u){
#pragma unroll
      for (int kxi = 0; kxi < 2; kxi++){
        int kx = px + 2*kxi, jx = (ix + 1 - kx) >> 1;
        if ((unsigned)jx < 128u){
          const float4* tb = (const float4*)&tt[(int)ib[(jy << 7) + jx]*260
                                                + (((ky << 2) + kx) << 4)];
          float4 t0 = tb[0], t1 = tb[1], t2 = tb[2], t3 = tb[3];
          d[0]  += t0.x; d[1]  += t0.y; d[2]  += t0.z; d[3]  += t0.w;
          d[4]  += t1.x; d[5]  += t1.y; d[6]  += t1.z; d[7]  += t1.w;
          d[8]  += t2.x; d[9]  += t2.y; d[10] += t2.z; d[11] += t2.w;
          d[12] += t3.x; d[13] += t3.y; d[14] += t3.z; d[15] += t3.w;
        }
      }
    }
  }
}

// ---------------- k7s: d1 stats + MATERIALIZE d1raw (into dead h1p) ---------
__global__ __launch_bounds__(256) void k7s(
    const unsigned char* __restrict__ idxb, const float* __restrict__ misc,
    float* __restrict__ d1, float* __restrict__ partd, float* __restrict__ qout)
{
  __shared__ __align__(16) float tt[780];
  __shared__ float red[128];
  const int b = blockIdx.x, t = threadIdx.x;
  for (int s = t; s < 780; s += 256) tt[s] = misc[400 + s];
  __syncthreads();
  if (b == 0 && t == 0) qout[0] = 1.2f * misc[192] * (1.0f/1048576.0f);
  float s[16], ss[16];
#pragma unroll
  for (int q = 0; q < 16; q++){ s[q] = 0.f; ss[q] = 0.f; }
  for (int k = 0; k < 4; k++){
    int p = (b << 10) + (k << 8) + t;
    int n = p >> 16, rem = p & 65535, iy = rem >> 8, ix = rem & 255;
    const unsigned char* ib = idxb + ((size_t)n << 14);
    float d[16];
#pragma unroll
    for (int q = 0; q < 16; q++) d[q] = 0.f;
    d1_accum(ib, iy, ix, tt, d);
    size_t base = ((size_t)(n*16) << 16) + (iy << 8) + ix;
#pragma unroll
    for (int q = 0; q < 16; q++){
      d1[base + ((size_t)q << 16)] = d[q];
      s[q] += d[q]; ss[q] += d[q]*d[q];
    }
  }
#pragma unroll
  for (int q = 0; q < 16; q++){ s[q] = wredf(s[q]); ss[q] = wredf(ss[q]); }
  const int w = t >> 6, l = t & 63;
  if (l == 0){
#pragma unroll
    for (int q = 0; q < 16; q++){ red[w*32 + q] = s[q]; red[w*32 + 16 + q] = ss[q]; }
  }
  __syncthreads();
  if (t < 32) partd[b*32 + t] = red[t] + red[32+t] + red[64+t] + red[96+t];
}

// ---------------- k9: convT2 direct-L1 from d1raw (zero LDS/barriers) -------
// Block: 4 out rows (rowq=wave) x 256 out cols. Per (kyi,ci): read d1 row
// through L1 (float2 + 2 clamped scalars; neighbors share cache lines),
// bn_d+relu at read (sd/shs via uniform s_load), 24-fmaf accumulate, tanh.
__global__ __launch_bounds__(256) void k9_dec(
    const float* __restrict__ d1, const float* __restrict__ misc,
    const float* __restrict__ wt9, const float* __restrict__ db2,
    float* __restrict__ out)
{
  const int b = blockIdx.x, t = threadIdx.x;
  const int n = b >> 8, r8 = b & 255, G = r8 >> 1, xh = r8 & 1;
  const int M0 = xh << 7;
  const int rowq = t >> 6, u = t & 63;
  const int oy2 = (G << 2) + rowq;
  const int py = (oy2 + 1) & 1;
  const int ixm = M0 + (u << 1);
  const bool okl = (ixm - 1) >= 0;            // false only u==0,xh==0
  const bool okr = (ixm + 2) < 256;           // false only u==63,xh==1
  const int ixl = okl ? (ixm - 1) : 0;
  const int ixr = okr ? (ixm + 2) : 255;
  float acc[2][2][3];
#pragma unroll
  for (int p2 = 0; p2 < 2; p2++)
#pragma unroll
    for (int e = 0; e < 2; e++)
#pragma unroll
      for (int c = 0; c < 3; c++) acc[p2][e][c] = 0.f;

#pragma unroll
  for (int kyi = 0; kyi < 2; kyi++){
    const int ky = py + (kyi << 1);
    const int iy = (oy2 + 1 - ky) >> 1;
    if ((unsigned)iy < 256u){                  // wave-uniform branch
      const float* R = d1 + ((size_t)(n*16) << 16) + (iy << 8);
      for (int ci = 0; ci < 16; ci++){
        const float sdv = misc[160 + ci], shv = misc[176 + ci]; // s_load
        const float* wp = &wt9[(ky*16 + ci)*12];                // s_load
        float w[12];
#pragma unroll
        for (int k = 0; k < 12; k++) w[k] = wp[k];
        const float* Rc = R + ((size_t)ci << 16);
        float2 m01 = *(const float2*)&Rc[ixm];
        float rl = Rc[ixl], rr = Rc[ixr];
        float v0 = okl ? fmaxf(fmaf(rl,    sdv, shv), 0.f) : 0.f;
        float v1 =       fmaxf(fmaf(m01.x, sdv, shv), 0.f);
        float v2 =       fmaxf(fmaf(m01.y, sdv, shv), 0.f);
        float v3 = okr ? fmaxf(fmaf(rr,    sdv, shv), 0.f) : 0.f;
        float v[4] = {v0, v1, v2, v3};
#pragma unroll
        for (int e = 0; e < 2; e++){
          float vmm = v[e], v0m = v[e+1], vp1 = v[e+2];
          acc[1][e][0] = fmaf(vp1, w[0], acc[1][e][0]);
          acc[1][e][1] = fmaf(vp1, w[1], acc[1][e][1]);
          acc[1][e][2] = fmaf(vp1, w[2], acc[1][e][2]);
          acc[0][e][0] = fmaf(v0m, w[3], acc[0][e][0]);
          acc[0][e][1] = fmaf(v0m, w[4], acc[0][e][1]);
          acc[0][e][2] = fmaf(v0m, w[5], acc[0][e][2]);
          acc[1][e][0] = fmaf(v0m, w[6], acc[1][e][0]);
          acc[1][e][1] = fmaf(v0m, w[7], acc[1][e][1]);
          acc[1][e][2] = fmaf(v0m, w[8], acc[1][e][2]);
          acc[0][e][0] = fmaf(vmm, w[9], acc[0][e][0]);
          acc[0][e][1] = fmaf(vmm, w[10], acc[0][e][1]);
          acc[0][e][2] = fmaf(vmm, w[11], acc[0][e][2]);
        }
      }
    }
  }
  const float bb[3] = {db2[0], db2[1], db2[2]};
#pragma unroll
  for (int co = 0; co < 3; co++){
    float4 o = make_float4(fast_tanh(acc[0][0][co] + bb[co]), fast_tanh(acc[1][0][co] + bb[co]),
                           fast_tanh(acc[0][1][co] + bb[co]), fast_tanh(acc[1][1][co] + bb[co]));
    *(float4*)&out[((size_t)(n*3 + co) << 18) + ((size_t)oy2 << 9) + (M0 << 1) + (u << 2)] = o;
  }
}

// ---------------------------------------------------------------------------
extern "C" void kernel_launch(void* const* d_in, const int* in_sizes, int n_in,
                              void* d_out, int out_size, void* d_ws, size_t ws_size,
                              hipStream_t stream)
{
  (void)in_sizes; (void)n_in; (void)out_size;
  const float* x       = (const float*)d_in[0];
  const float* enc_w1  = (const float*)d_in[1];
  const float* enc_g1  = (const float*)d_in[3];
  const float* enc_be1 = (const float*)d_in[4];
  const float* enc_w2  = (const float*)d_in[5];
  const float* enc_g2  = (const float*)d_in[7];
  const float* enc_be2 = (const float*)d_in[8];
  const float* preq_w  = (const float*)d_in[9];
  const float* preq_b  = (const float*)d_in[10];
  const float* emb     = (const float*)d_in[11];
  const float* postq_w = (const float*)d_in[12];
  const float* postq_b = (const float*)d_in[13];
  const float* dec_w1  = (const float*)d_in[14];
  const float* dec_g1  = (const float*)d_in[16];
  const float* dec_be1 = (const float*)d_in[17];
  const float* dec_w2  = (const float*)d_in[18];
  const float* dec_b2  = (const float*)d_in[19];
  float* out = (float*)d_out;
  char*  ws  = (char*)d_ws;

  float* h1p = (float*)ws;                         // 134217728 B (later d1raw)
  float* h2  = (float*)(ws + 134217728);           // 134217728 B
  size_t ebase = (ws_size - 4194304) & ~(size_t)255;
  unsigned char* idxb = (unsigned char*)(ws + ebase);            // 512 KB
  float* part1 = (float*)(ws + ebase + 524288);                  // 512 KB
  float* partd = (float*)(ws + ebase + 1048576);                 // 256 KB
  float* misc  = (float*)(ws + ebase + 1310720);                 // 8 KB
  float* wt1   = (float*)(ws + ebase + 1318912);                 // 3 KB
  float* wt2   = (float*)(ws + ebase + 1327104);                 // 64 KB
  float* wt9   = (float*)(ws + ebase + 1392640);                 // 3 KB
  float* part2 = out;   // 4 MB, overwritten by k9's recon afterwards
  float* d1raw = h1p;   // h1p dead after k3/k5 -> reuse for d1 (exactly 128MiB)

  kP<<<64, 256, 0, stream>>>(enc_w1, enc_w2, dec_w2,
                             postq_w, postq_b, emb, wt1, wt2, wt9, misc);
  k6b_tt<<<768, 64, 0, stream>>>(dec_w1, misc);
  k1_conv1<<<4096, 256, 0, stream>>>(x, wt1, h1p, part1);
  k_stats<<<16, 256, 0, stream>>>(part1, 4096, 32, 0, enc_g1, enc_be1,
                                  misc + 0, misc + 16, 1.f/2097152.f);
  k3_conv2<<<2048, 256, 0, stream>>>(h1p, wt2, misc, h2, part2);
  k_stats<<<64, 256, 0, stream>>>(part2, 2048, 128, 1, enc_g2, enc_be2,
                                  misc + 32, misc + 96, 1.f/524288.f);
  k5_vq<<<1024, 256, 0, stream>>>(h2, misc, preq_w, preq_b, emb, idxb, misc + 192);
  k7s<<<2048, 256, 0, stream>>>(idxb, misc, d1raw, partd, out + 25165824);
  k_stats<<<16, 256, 0, stream>>>(partd, 2048, 32, 0, dec_g1, dec_be1,
                                  misc + 160, misc + 176, 1.f/2097152.f);
  k9_dec<<<8192, 256, 0, stream>>>(d1raw, misc, wt9, dec_b2, out);
}

// Round 16
// 469.897 us; speedup vs baseline: 1.6897x; 1.6897x over previous
//
#include <hip/hip_runtime.h>
#include <hip/hip_bf16.h>

// VQVAE forward, MI355X, fp32 encoder path (argmin stability).
// v16 = v15 with the decoder layout fixed: k7s materializes d1 CHANNEL-LAST
// (d1cl[n][iy][ix][ci16], 64B/pixel, write addr = p<<4 contiguous); k9 is a
// zero-LDS streaming kernel: <=6 input pixels x 4 consecutive float4 reads,
// bn_d+relu at read, per-(ky,kx) 48-weight s_load blocks, static indices
// (~40 VGPR). Decoder reassociation is post-argmin (noise ~1e-6 << thr).
// Encoder path identical to v14/v15 (argmin-stable).
// enc_b1/enc_b2/dec_b1 cancelled by training-mode BN -> unused.

#define EPSB 1e-5f

__device__ __forceinline__ float wredf(float v){
#pragma unroll
  for (int m = 32; m >= 1; m >>= 1) v += __shfl_xor(v, m, 64);
  return v;
}

__device__ __forceinline__ float fast_tanh(float x){
  float e = __expf(2.f * x);
  return fmaf(-2.f, __builtin_amdgcn_rcpf(e + 1.f), 1.f);
}

// act[16] = relu(bn(d1cl pixel)) ; all static indices
__device__ __forceinline__ void d1_act(const float* __restrict__ p,
    const float* __restrict__ misc, float* __restrict__ a){
  const float4* P = (const float4*)p;
  float4 v0 = P[0], v1 = P[1], v2 = P[2], v3 = P[3];
  float vv[16] = {v0.x, v0.y, v0.z, v0.w, v1.x, v1.y, v1.z, v1.w,
                  v2.x, v2.y, v2.z, v2.w, v3.x, v3.y, v3.z, v3.w};
#pragma unroll
  for (int ci = 0; ci < 16; ci++)
    a[ci] = fmaxf(fmaf(vv[ci], misc[160 + ci], misc[176 + ci]), 0.f);
}

// acc[0..2] += sum_ci a[ci] * wp[ci*3+co]   (wp uniform -> s_load)
__device__ __forceinline__ void wacc(const float* __restrict__ a,
    const float* __restrict__ wp, float* __restrict__ acc){
#pragma unroll
  for (int ci = 0; ci < 16; ci++){
    acc[0] = fmaf(a[ci], wp[ci*3 + 0], acc[0]);
    acc[1] = fmaf(a[ci], wp[ci*3 + 1], acc[1]);
    acc[2] = fmaf(a[ci], wp[ci*3 + 2], acc[2]);
  }
}

// ---------------- kP: weight transposes + P table + qsum=0 ------------------
__global__ __launch_bounds__(256) void kP(
    const float* __restrict__ w1, const float* __restrict__ w2,
    const float* __restrict__ dw2,
    const float* __restrict__ pqw, const float* __restrict__ pqb,
    const float* __restrict__ emb,
    float* __restrict__ wt1, float* __restrict__ wt2,
    float* __restrict__ wt9, float* __restrict__ misc)
{
  const int b = blockIdx.x, t = threadIdx.x;
  const int s = b*256 + t;                       // 0..16383
  { int tap = s >> 6, co = s & 63;               // wt2[tap=ci*16+ky*4+kx][co64]
    int ci = tap >> 4, ky = (tap >> 2) & 3, kx = tap & 3;
    wt2[s] = w2[((co*16 + ci)*4 + ky)*4 + kx]; }
  if (b == 0){
    for (int s2 = t; s2 < 768; s2 += 256){
      int tap = s2 >> 4, co = s2 & 15;           // wt1[tap][co16]
      int ci = tap >> 4, ky = (tap >> 2) & 3, kx = tap & 3;
      wt1[s2] = w1[((co*3 + ci)*4 + ky)*4 + kx];
      // wt9b[((ky*4+kx)*16+ci)*3+co] = dec_w2[ci][co][ky][kx]
      int co9 = s2 % 3, r3 = s2 / 3;
      int ci9 = r3 & 15, kykx = r3 >> 4;
      int ky9 = kykx >> 2, kx9 = kykx & 3;
      wt9[s2] = dw2[((ci9*3 + co9)*4 + ky9)*4 + kx9];
    }
    if (t < 192){                                // P[i][ci] = postq(emb[i])
      int i = t >> 6, ci = t & 63;
      misc[200 + t] = fmaf(pqw[ci*2], emb[i*2],
                      fmaf(pqw[ci*2 + 1], emb[i*2 + 1], pqb[ci]));
    }
    if (t == 255) misc[192] = 0.f;               // qloss accumulator
  }
}

// ---------------- k6b: TT[i][ky][kx][oc] = sum_ci dec_w1 * P (parallel) -----
__global__ __launch_bounds__(64) void k6b_tt(
    const float* __restrict__ dw1, float* __restrict__ misc)
{
  const int e = blockIdx.x;                 // i*256 + (ky*4+kx)*16 + oc
  const int i = e >> 8, rem = e & 255;
  const int kykx = rem >> 4, oc = rem & 15;
  const int ky = kykx >> 2, kx = kykx & 3;
  const int l = threadIdx.x;                // ci (0..63)
  float v = dw1[((l*16 + oc)*4 + ky)*4 + kx] * misc[200 + i*64 + l];
  v = wredf(v);
  if (l == 0) misc[400 + i*260 + rem] = v;  // stride 260 pad (1040B, 16B-mult)
}

// ---------------- k1: conv1 3->16 s2 p1 -> parity-split h1p + stats ----------
// h1p[n][co16][yp][xp][128][128]; yp=oy&1, xp=ox&1.
__global__ __launch_bounds__(256) void k1_conv1(
    const float* __restrict__ x, const float* __restrict__ wt1,
    float* __restrict__ h1p, float* __restrict__ part1)
{
  __shared__ __align__(16) float xt[3*6*516];
  __shared__ float red[128];
  const int b = blockIdx.x, t = threadIdx.x;
  const int n = b >> 7, yt = b & 127;
  const int oy0 = yt << 1, iy0 = (oy0 << 1) - 1;
  const int rh = t >> 7, l128 = t & 127, c4 = l128 << 2;
#pragma unroll
  for (int rp = 0; rp < 9; rp++){
    int rIdx = (rp << 1) + rh;              // 0..17 = ci*6+rr
    int ci = rIdx / 6, rr = rIdx - ci*6;
    int iy = iy0 + rr;
    bool yok = (unsigned)iy < 512u;
    const float* xr = x + (((size_t)(n*3 + ci)) << 18) + ((size_t)(iy & 511) << 9);
    float* dst = &xt[rIdx*516];
    float4 v = make_float4(0.f, 0.f, 0.f, 0.f);
    if (yok) v = *(const float4*)&xr[c4];
    dst[c4 + 1] = v.x; dst[c4 + 2] = v.y; dst[c4 + 3] = v.z; dst[c4 + 4] = v.w;
    if (l128 == 0){ dst[0] = 0.f; dst[513] = 0.f; }
  }
  __syncthreads();
  const int w = t >> 6, l = t & 63;
  const int oyr = w & 1, xh = w >> 1;
  float acc[2][16];
#pragma unroll
  for (int j = 0; j < 2; j++)
#pragma unroll
    for (int q = 0; q < 16; q++) acc[j][q] = 0.f;

  for (int ci = 0; ci < 3; ci++){
    for (int ky = 0; ky < 4; ky++){
      const float* xrow = &xt[(ci*6 + (oyr << 1) + ky)*516];
      float v[2][4];
#pragma unroll
      for (int j = 0; j < 2; j++){
        int ox = (xh << 7) + (j << 6) + l;
        float2 p0 = *(const float2*)&xrow[2*ox];
        float2 p1 = *(const float2*)&xrow[2*ox + 2];
        v[j][0] = p0.x; v[j][1] = p0.y; v[j][2] = p1.x; v[j][3] = p1.y;
      }
      const float* wb = &wt1[((ci*4 + ky) << 6)];
#pragma unroll
      for (int kx = 0; kx < 4; kx++){
        const float* wp = wb + (kx << 4);        // uniform -> s_load
        float wv[16];
#pragma unroll
        for (int q = 0; q < 16; q++) wv[q] = wp[q];
#pragma unroll
        for (int j = 0; j < 2; j++)
#pragma unroll
          for (int q = 0; q < 16; q++) acc[j][q] = fmaf(v[j][kx], wv[q], acc[j][q]);
      }
    }
  }
  float s[16], ss[16];
#pragma unroll
  for (int q = 0; q < 16; q++){ s[q] = 0.f; ss[q] = 0.f; }
  const int xp = l & 1;
#pragma unroll
  for (int j = 0; j < 2; j++){
    int m = (xh << 6) + (j << 5) + (l >> 1);
#pragma unroll
    for (int q = 0; q < 16; q++){
      float vv = acc[j][q];
      h1p[((((size_t)(n*16 + q) << 1) + oyr) << 15) + ((size_t)xp << 14) + (yt << 7) + m] = vv;
      s[q] += vv; ss[q] += vv*vv;
    }
  }
#pragma unroll
  for (int q = 0; q < 16; q++){ s[q] = wredf(s[q]); ss[q] = wredf(ss[q]); }
  if (l == 0){
#pragma unroll
    for (int q = 0; q < 16; q++){ red[w*32 + q] = s[q]; red[w*32 + 16 + q] = ss[q]; }
  }
  __syncthreads();
  if (t < 32) part1[b*32 + t] = red[t] + red[32+t] + red[64+t] + red[96+t];
}

// ---------------- reduce partials -> scale/shift (BN) ------------------------
__global__ __launch_bounds__(256) void k_stats(
    const float* __restrict__ part, int nslots, int slotstride, int grouped,
    const float* __restrict__ g, const float* __restrict__ be,
    float* __restrict__ scale, float* __restrict__ shift, float Ninv)
{
  const int c = blockIdx.x, t = threadIdx.x;
  const int off = grouped ? ((c >> 4) << 5) : 0;
  const int ci = grouped ? (c & 15) : c;
  float S = 0.f, SS = 0.f;
  for (int q = t; q < nslots; q += 256){
    const float* pp = &part[(size_t)q * slotstride + off];
    S += pp[ci]; SS += pp[16 + ci];
  }
  S = wredf(S); SS = wredf(SS);
  __shared__ float sb[8];
  if ((t & 63) == 0){ sb[t >> 6] = S; sb[4 + (t >> 6)] = SS; }
  __syncthreads();
  if (t == 0){
    float Sv = sb[0]+sb[1]+sb[2]+sb[3], SSv = sb[4]+sb[5]+sb[6]+sb[7];
    float m = Sv * Ninv;
    float var = SSv * Ninv - m*m;
    float sc = g[c] * rsqrtf(var + EPSB);
    scale[c] = sc;
    shift[c] = be[c] - m * sc;
  }
}

// ---------------- k3: conv2 16->64 s2 p1 — direct-L1, zero staging ----------
__global__ __launch_bounds__(256) void k3_conv2(
    const float* __restrict__ h1p, const float* __restrict__ wt2,
    const float* __restrict__ misc, float* __restrict__ h2,
    float* __restrict__ part2)
{
  __shared__ float red[128];
  const int b = blockIdx.x, t = threadIdx.x;
  const int n = b >> 6, yt = b & 63;
  const int oy0 = yt << 1;
  const int w = __builtin_amdgcn_readfirstlane(t >> 6);  // co-group
  const int l = t & 63, oyr = l >> 5, lx = l & 31;
  float acc[4][16];
#pragma unroll
  for (int e = 0; e < 4; e++)
#pragma unroll
    for (int q = 0; q < 16; q++) acc[e][q] = 0.f;

  const int myk[4] = {oy0 + oyr - 1, oy0 + oyr, oy0 + oyr, oy0 + oyr + 1};
  const int ypk[4] = {1, 0, 1, 0};
  const int lxo = lx << 2;

  for (int g = 0; g < 16; g++){
    const float sc = misc[g], sh = misc[16 + g];         // uniform -> s_load
    const float* pg = h1p + (((size_t)(n*16 + g)) << 16);
#pragma unroll
    for (int ky = 0; ky < 4; ky++){
      const int m_y = myk[ky];
      const bool rv = (unsigned)m_y < 128u;
      const int myc = m_y & 127;
      const float scv = rv ? sc : 0.f, shv = rv ? sh : 0.f;
      const float* rb = pg + ((size_t)ypk[ky] << 15) + (myc << 7) + lxo;
      float4 R0 = *(const float4*)rb;              // xp0 m..m+3
      float4 R1 = *(const float4*)(rb + 16384);    // xp1 m..m+3
      float A0x = fmaxf(fmaf(R0.x, scv, shv), 0.f);
      float A0y = fmaxf(fmaf(R0.y, scv, shv), 0.f);
      float A0z = fmaxf(fmaf(R0.z, scv, shv), 0.f);
      float A0w = fmaxf(fmaf(R0.w, scv, shv), 0.f);
      float A1x = fmaxf(fmaf(R1.x, scv, shv), 0.f);
      float A1y = fmaxf(fmaf(R1.y, scv, shv), 0.f);
      float A1z = fmaxf(fmaf(R1.z, scv, shv), 0.f);
      float A1w = fmaxf(fmaf(R1.w, scv, shv), 0.f);
      float nx0 = __shfl_down(A0x, 1, 64);  if (lx == 31) nx0 = 0.f;
      float pv1 = __shfl_up(A1w, 1, 64);    if (lx == 0)  pv1 = 0.f;
      float act0[4] = {pv1, A1x, A1y, A1z};   // kx=0: xp1 m-1
      float act1[4] = {A0x, A0y, A0z, A0w};   // kx=1: xp0 m
      float act2[4] = {A1x, A1y, A1z, A1w};   // kx=2: xp1 m
      float act3[4] = {A0y, A0z, A0w, nx0};   // kx=3: xp0 m+1
      const float* wb = &wt2[(((g << 4) + (ky << 2)) << 6) + (w << 4)];
#pragma unroll
      for (int kx = 0; kx < 4; kx++){
        const float* wp = wb + (kx << 6);      // uniform -> s_load x16
        float wv[16];
#pragma unroll
        for (int q = 0; q < 16; q++) wv[q] = wp[q];
        const float* av = (kx == 0) ? act0 : (kx == 1) ? act1 : (kx == 2) ? act2 : act3;
#pragma unroll
        for (int e = 0; e < 4; e++)
#pragma unroll
          for (int q = 0; q < 16; q++)
            acc[e][q] = fmaf(av[e], wv[q], acc[e][q]);
      }
    }
  }
  const int oy = oy0 + oyr;
  float s[16], ss[16];
#pragma unroll
  for (int q = 0; q < 16; q++){ s[q] = 0.f; ss[q] = 0.f; }
#pragma unroll
  for (int e = 0; e < 4; e++)
#pragma unroll
    for (int q = 0; q < 16; q++){ float v = acc[e][q]; s[q] += v; ss[q] += v*v; }
#pragma unroll
  for (int q = 0; q < 16; q++){
    float4 o = make_float4(acc[0][q], acc[1][q], acc[2][q], acc[3][q]);
    *(float4*)&h2[(((size_t)(n*64) + (w << 4) + q) << 14) + (oy << 7) + (lx << 2)] = o;
  }
#pragma unroll
  for (int q = 0; q < 16; q++){ s[q] = wredf(s[q]); ss[q] = wredf(ss[q]); }
  if (l == 0){
#pragma unroll
    for (int q = 0; q < 16; q++){ red[w*32 + q] = s[q]; red[w*32 + 16 + q] = ss[q]; }
  }
  __syncthreads();
  if (t < 128) part2[b*128 + t] = red[t];
}

// ---------------- k5: preq(bn2+relu fused) + VQ argmin + qloss + idx ---------
__global__ __launch_bounds__(256) void k5_vq(
    const float* __restrict__ h2, const float* __restrict__ misc,
    const float* __restrict__ pw, const float* __restrict__ pb,
    const float* __restrict__ emb, unsigned char* __restrict__ idxb,
    float* __restrict__ qsum)
{
  __shared__ float eb[4];
  const int t = threadIdx.x;
  const int p0 = blockIdx.x*512 + (t << 1);
  const int n = p0 >> 14, pos = p0 & 16383;
  const float* hp = h2 + ((size_t)n << 20) + pos;
  float q0[2], q1[2];
  const float pb0 = pb[0], pb1 = pb[1];
#pragma unroll
  for (int j = 0; j < 2; j++){ q0[j] = pb0; q1[j] = pb1; }
  for (int c = 0; c < 64; c++){
    float2 v = *(const float2*)&hp[(size_t)c << 14];
    float sc = misc[32 + c], sh = misc[96 + c];   // uniform -> s_load
    float w0 = pw[c], w1 = pw[64 + c];            // uniform -> s_load
    float a0 = fmaxf(fmaf(v.x, sc, sh), 0.f);
    float a1 = fmaxf(fmaf(v.y, sc, sh), 0.f);
    q0[0] = fmaf(a0, w0, q0[0]); q1[0] = fmaf(a0, w1, q1[0]);
    q0[1] = fmaf(a1, w0, q0[1]); q1[1] = fmaf(a1, w1, q1[1]);
  }
  const float e00 = emb[0], e01 = emb[1], e10 = emb[2], e11 = emb[3],
              e20 = emb[4], e21 = emb[5];
  float esum = 0.f;
  unsigned char bi[2];
#pragma unroll
  for (int j = 0; j < 2; j++){
    float dx0 = q0[j]-e00, dy0 = q1[j]-e01;
    float dx1 = q0[j]-e10, dy1 = q1[j]-e11;
    float dx2 = q0[j]-e20, dy2 = q1[j]-e21;
    float d0 = dx0*dx0+dy0*dy0, d1 = dx1*dx1+dy1*dy1, d2 = dx2*dx2+dy2*dy2;
    int bj = 0; float db = d0;
    if (d1 < db){ db = d1; bj = 1; }
    if (d2 < db){ db = d2; bj = 2; }
    bi[j] = (unsigned char)bj; esum += db;
  }
  *(uchar2*)&idxb[p0] = make_uchar2(bi[0], bi[1]);
  float e = wredf(esum);
  if ((t & 63) == 0) eb[t >> 6] = e;
  __syncthreads();
  if (t == 0) atomicAdd(qsum, eb[0]+eb[1]+eb[2]+eb[3]);
}

// d1raw at (iy,ix): sum of <=4 TT entries via idx map (convT1 collapsed).
__device__ __forceinline__ void d1_accum(const unsigned char* __restrict__ ib,
    int iy, int ix, const float* __restrict__ tt, float* __restrict__ d)
{
  const int py = (iy + 1) & 1, px = (ix + 1) & 1;
#pragma unroll
  for (int kyi = 0; kyi < 2; kyi++){
    int ky = py + 2*kyi, jy = (iy + 1 - ky) >> 1;
    if ((unsigned)jy < 128u){
#pragma unroll
      for (int kxi = 0; kxi < 2; kxi++){
        int kx = px + 2*kxi, jx = (ix + 1 - kx) >> 1;
        if ((unsigned)jx < 128u){
          const float4* tb = (const float4*)&tt[(int)ib[(jy << 7) + jx]*260
                                                + (((ky << 2) + kx) << 4)];
          float4 t0 = tb[0], t1 = tb[1], t2 = tb[2], t3 = tb[3];
          d[0]  += t0.x; d[1]  += t0.y; d[2]  += t0.z; d[3]  += t0.w;
          d[4]  += t1.x; d[5]  += t1.y; d[6]  += t1.z; d[7]  += t1.w;
          d[8]  += t2.x; d[9]  += t2.y; d[10] += t2.z; d[11] += t2.w;
          d[12] += t3.x; d[13] += t3.y; d[14] += t3.z; d[15] += t3.w;
        }
      }
    }
  }
}

// ---------------- k7s: d1 stats + materialize CHANNEL-LAST d1cl -------------
// d1cl[p*16 + q], p = (n<<16)+(iy<<8)+ix -> write addr = p<<4, contiguous.
__global__ __launch_bounds__(256) void k7s(
    const unsigned char* __restrict__ idxb, const float* __restrict__ misc,
    float* __restrict__ d1cl, float* __restrict__ partd, float* __restrict__ qout)
{
  __shared__ __align__(16) float tt[780];
  __shared__ float red[128];
  const int b = blockIdx.x, t = threadIdx.x;
  for (int s = t; s < 780; s += 256) tt[s] = misc[400 + s];
  __syncthreads();
  if (b == 0 && t == 0) qout[0] = 1.2f * misc[192] * (1.0f/1048576.0f);
  float s[16], ss[16];
#pragma unroll
  for (int q = 0; q < 16; q++){ s[q] = 0.f; ss[q] = 0.f; }
  for (int k = 0; k < 4; k++){
    int p = (b << 10) + (k << 8) + t;
    int n = p >> 16, rem = p & 65535, iy = rem >> 8, ix = rem & 255;
    const unsigned char* ib = idxb + ((size_t)n << 14);
    float d[16];
#pragma unroll
    for (int q = 0; q < 16; q++) d[q] = 0.f;
    d1_accum(ib, iy, ix, tt, d);
    float4* dp = (float4*)&d1cl[(size_t)p << 4];
    dp[0] = make_float4(d[0],  d[1],  d[2],  d[3]);
    dp[1] = make_float4(d[4],  d[5],  d[6],  d[7]);
    dp[2] = make_float4(d[8],  d[9],  d[10], d[11]);
    dp[3] = make_float4(d[12], d[13], d[14], d[15]);
#pragma unroll
    for (int q = 0; q < 16; q++){ s[q] += d[q]; ss[q] += d[q]*d[q]; }
  }
#pragma unroll
  for (int q = 0; q < 16; q++){ s[q] = wredf(s[q]); ss[q] = wredf(ss[q]); }
  const int w = t >> 6, l = t & 63;
  if (l == 0){
#pragma unroll
    for (int q = 0; q < 16; q++){ red[w*32 + q] = s[q]; red[w*32 + 16 + q] = ss[q]; }
  }
  __syncthreads();
  if (t < 32) partd[b*32 + t] = red[t] + red[32+t] + red[64+t] + red[96+t];
}

// ---------------- k9: convT2 streaming from channel-last d1cl + tanh --------
// Block = one out row (n, oy); thread m handles out cols 2m, 2m+1, all 3 co.
// ky = oy+1-2iy (2 valid ky per oy); col 2m <- kx in {1,3} (ix=m, m-1);
// col 2m+1 <- kx in {0,2} (ix=m, m+1). <=6 pixels x 4 float4 each.
__global__ __launch_bounds__(256) void k9_dec(
    const float* __restrict__ d1cl, const float* __restrict__ misc,
    const float* __restrict__ wt9b, const float* __restrict__ db2,
    float* __restrict__ out)
{
  const int b = blockIdx.x, m = threadIdx.x;
  const int n = b >> 9, oy = b & 511;
  const int py = (oy + 1) & 1;
  float accA[3] = {0.f, 0.f, 0.f};   // out col 2m
  float accB[3] = {0.f, 0.f, 0.f};   // out col 2m+1
#pragma unroll
  for (int kyi = 0; kyi < 2; kyi++){
    const int ky = py + (kyi << 1);
    const int iy = (oy + 1 - ky) >> 1;
    if ((unsigned)iy < 256u){                     // wave-uniform
      const float* rbp = d1cl + (((size_t)((n << 16) + (iy << 8))) << 4);
      float a[16];
      d1_act(rbp + ((size_t)m << 4), misc, a);    // ix = m
      wacc(a, &wt9b[(((ky << 2) + 1) << 4)*3], accA);   // kx=1 -> col 2m
      wacc(a, &wt9b[(((ky << 2) + 2) << 4)*3], accB);   // kx=2 -> col 2m+1
      if (m > 0){                                 // ix = m-1, kx=3 -> col 2m
        d1_act(rbp + ((size_t)(m - 1) << 4), misc, a);
        wacc(a, &wt9b[(((ky << 2) + 3) << 4)*3], accA);
      }
      if (m < 255){                               // ix = m+1, kx=0 -> col 2m+1
        d1_act(rbp + ((size_t)(m + 1) << 4), misc, a);
        wacc(a, &wt9b[(((ky << 2) + 0) << 4)*3], accB);
      }
    }
  }
#pragma unroll
  for (int co = 0; co < 3; co++){
    const float bb = db2[co];
    float2 o = make_float2(fast_tanh(accA[co] + bb), fast_tanh(accB[co] + bb));
    *(float2*)&out[((size_t)(n*3 + co) << 18) + ((size_t)oy << 9) + (m << 1)] = o;
  }
}

// ---------------------------------------------------------------------------
extern "C" void kernel_launch(void* const* d_in, const int* in_sizes, int n_in,
                              void* d_out, int out_size, void* d_ws, size_t ws_size,
                              hipStream_t stream)
{
  (void)in_sizes; (void)n_in; (void)out_size;
  const float* x       = (const float*)d_in[0];
  const float* enc_w1  = (const float*)d_in[1];
  const float* enc_g1  = (const float*)d_in[3];
  const float* enc_be1 = (const float*)d_in[4];
  const float* enc_w2  = (const float*)d_in[5];
  const float* enc_g2  = (const float*)d_in[7];
  const float* enc_be2 = (const float*)d_in[8];
  const float* preq_w  = (const float*)d_in[9];
  const float* preq_b  = (const float*)d_in[10];
  const float* emb     = (const float*)d_in[11];
  const float* postq_w = (const float*)d_in[12];
  const float* postq_b = (const float*)d_in[13];
  const float* dec_w1  = (const float*)d_in[14];
  const float* dec_g1  = (const float*)d_in[16];
  const float* dec_be1 = (const float*)d_in[17];
  const float* dec_w2  = (const float*)d_in[18];
  const float* dec_b2  = (const float*)d_in[19];
  float* out = (float*)d_out;
  char*  ws  = (char*)d_ws;

  float* h1p = (float*)ws;                         // 134217728 B (later d1cl)
  float* h2  = (float*)(ws + 134217728);           // 134217728 B
  size_t ebase = (ws_size - 4194304) & ~(size_t)255;
  unsigned char* idxb = (unsigned char*)(ws + ebase);            // 512 KB
  float* part1 = (float*)(ws + ebase + 524288);                  // 512 KB
  float* partd = (float*)(ws + ebase + 1048576);                 // 256 KB
  float* misc  = (float*)(ws + ebase + 1310720);                 // 8 KB
  float* wt1   = (float*)(ws + ebase + 1318912);                 // 3 KB
  float* wt2   = (float*)(ws + ebase + 1327104);                 // 64 KB
  float* wt9   = (float*)(ws + ebase + 1392640);                 // 3 KB
  float* part2 = out;   // 4 MB, overwritten by k9's recon afterwards
  float* d1cl  = h1p;   // h1p dead after k3 -> reuse (exactly 128 MiB)

  kP<<<64, 256, 0, stream>>>(enc_w1, enc_w2, dec_w2,
                             postq_w, postq_b, emb, wt1, wt2, wt9, misc);
  k6b_tt<<<768, 64, 0, stream>>>(dec_w1, misc);
  k1_conv1<<<4096, 256, 0, stream>>>(x, wt1, h1p, part1);
  k_stats<<<16, 256, 0, stream>>>(part1, 4096, 32, 0, enc_g1, enc_be1,
                                  misc + 0, misc + 16, 1.f/2097152.f);
  k3_conv2<<<2048, 256, 0, stream>>>(h1p, wt2, misc, h2, part2);
  k_stats<<<64, 256, 0, stream>>>(part2, 2048, 128, 1, enc_g2, enc_be2,
                                  misc + 32, misc + 96, 1.f/524288.f);
  k5_vq<<<1024, 256, 0, stream>>>(h2, misc, preq_w, preq_b, emb, idxb, misc + 192);
  k7s<<<2048, 256, 0, stream>>>(idxb, misc, d1cl, partd, out + 25165824);
  k_stats<<<16, 256, 0, stream>>>(partd, 2048, 32, 0, dec_g1, dec_be1,
                                  misc + 160, misc + 176, 1.f/2097152.f);
  k9_dec<<<16384, 256, 0, stream>>>(d1cl, misc, wt9, dec_b2, out);
}

// Round 17
// 455.373 us; speedup vs baseline: 1.7436x; 1.0319x over previous
//
#include <hip/hip_runtime.h>
#include <hip/hip_bf16.h>
#include <hip/hip_fp16.h>

// VQVAE forward, MI355X, fp32 encoder path (argmin stability).
// v17 = v16 + (a) d1cl stored as fp16 (decoder-only, post-argmin; stats
// computed in fp32 before packing; recon impact ~1e-3 << 0.0121 thr) ->
// halves d1 write+read traffic; (b) k3 g-loop unroll 2 for deeper load/FMA
// overlap. Encoder path bit-identical to v14/v15/v16 (argmin-stable).
// enc_b1/enc_b2/dec_b1 cancelled by training-mode BN -> unused.

#define EPSB 1e-5f

__device__ __forceinline__ float wredf(float v){
#pragma unroll
  for (int m = 32; m >= 1; m >>= 1) v += __shfl_xor(v, m, 64);
  return v;
}

__device__ __forceinline__ float fast_tanh(float x){
  float e = __expf(2.f * x);
  return fmaf(-2.f, __builtin_amdgcn_rcpf(e + 1.f), 1.f);
}

// act[16] = relu(bn(fp16 d1 pixel)) ; all static indices
__device__ __forceinline__ void d1_act_h(const __half* __restrict__ p,
    const float* __restrict__ misc, float* __restrict__ a){
  union { uint4 u[2]; __half2 h[8]; } pk;
  const uint4* U = (const uint4*)p;
  pk.u[0] = U[0]; pk.u[1] = U[1];
#pragma unroll
  for (int j = 0; j < 8; j++){
    float2 f = __half22float2(pk.h[j]);
    a[2*j]     = fmaxf(fmaf(f.x, misc[160 + 2*j],     misc[176 + 2*j]),     0.f);
    a[2*j + 1] = fmaxf(fmaf(f.y, misc[160 + 2*j + 1], misc[176 + 2*j + 1]), 0.f);
  }
}

// acc[0..2] += sum_ci a[ci] * wp[ci*3+co]   (wp uniform -> s_load)
__device__ __forceinline__ void wacc(const float* __restrict__ a,
    const float* __restrict__ wp, float* __restrict__ acc){
#pragma unroll
  for (int ci = 0; ci < 16; ci++){
    acc[0] = fmaf(a[ci], wp[ci*3 + 0], acc[0]);
    acc[1] = fmaf(a[ci], wp[ci*3 + 1], acc[1]);
    acc[2] = fmaf(a[ci], wp[ci*3 + 2], acc[2]);
  }
}

// ---------------- kP: weight transposes + P table + qsum=0 ------------------
__global__ __launch_bounds__(256) void kP(
    const float* __restrict__ w1, const float* __restrict__ w2,
    const float* __restrict__ dw2,
    const float* __restrict__ pqw, const float* __restrict__ pqb,
    const float* __restrict__ emb,
    float* __restrict__ wt1, float* __restrict__ wt2,
    float* __restrict__ wt9, float* __restrict__ misc)
{
  const int b = blockIdx.x, t = threadIdx.x;
  const int s = b*256 + t;                       // 0..16383
  { int tap = s >> 6, co = s & 63;               // wt2[tap=ci*16+ky*4+kx][co64]
    int ci = tap >> 4, ky = (tap >> 2) & 3, kx = tap & 3;
    wt2[s] = w2[((co*16 + ci)*4 + ky)*4 + kx]; }
  if (b == 0){
    for (int s2 = t; s2 < 768; s2 += 256){
      int tap = s2 >> 4, co = s2 & 15;           // wt1[tap][co16]
      int ci = tap >> 4, ky = (tap >> 2) & 3, kx = tap & 3;
      wt1[s2] = w1[((co*3 + ci)*4 + ky)*4 + kx];
      // wt9b[((ky*4+kx)*16+ci)*3+co] = dec_w2[ci][co][ky][kx]
      int co9 = s2 % 3, r3 = s2 / 3;
      int ci9 = r3 & 15, kykx = r3 >> 4;
      int ky9 = kykx >> 2, kx9 = kykx & 3;
      wt9[s2] = dw2[((ci9*3 + co9)*4 + ky9)*4 + kx9];
    }
    if (t < 192){                                // P[i][ci] = postq(emb[i])
      int i = t >> 6, ci = t & 63;
      misc[200 + t] = fmaf(pqw[ci*2], emb[i*2],
                      fmaf(pqw[ci*2 + 1], emb[i*2 + 1], pqb[ci]));
    }
    if (t == 255) misc[192] = 0.f;               // qloss accumulator
  }
}

// ---------------- k6b: TT[i][ky][kx][oc] = sum_ci dec_w1 * P (parallel) -----
__global__ __launch_bounds__(64) void k6b_tt(
    const float* __restrict__ dw1, float* __restrict__ misc)
{
  const int e = blockIdx.x;                 // i*256 + (ky*4+kx)*16 + oc
  const int i = e >> 8, rem = e & 255;
  const int kykx = rem >> 4, oc = rem & 15;
  const int ky = kykx >> 2, kx = kykx & 3;
  const int l = threadIdx.x;                // ci (0..63)
  float v = dw1[((l*16 + oc)*4 + ky)*4 + kx] * misc[200 + i*64 + l];
  v = wredf(v);
  if (l == 0) misc[400 + i*260 + rem] = v;  // stride 260 pad (1040B, 16B-mult)
}

// ---------------- k1: conv1 3->16 s2 p1 -> parity-split h1p + stats ----------
// h1p[n][co16][yp][xp][128][128]; yp=oy&1, xp=ox&1.
__global__ __launch_bounds__(256) void k1_conv1(
    const float* __restrict__ x, const float* __restrict__ wt1,
    float* __restrict__ h1p, float* __restrict__ part1)
{
  __shared__ __align__(16) float xt[3*6*516];
  __shared__ float red[128];
  const int b = blockIdx.x, t = threadIdx.x;
  const int n = b >> 7, yt = b & 127;
  const int oy0 = yt << 1, iy0 = (oy0 << 1) - 1;
  const int rh = t >> 7, l128 = t & 127, c4 = l128 << 2;
#pragma unroll
  for (int rp = 0; rp < 9; rp++){
    int rIdx = (rp << 1) + rh;              // 0..17 = ci*6+rr
    int ci = rIdx / 6, rr = rIdx - ci*6;
    int iy = iy0 + rr;
    bool yok = (unsigned)iy < 512u;
    const float* xr = x + (((size_t)(n*3 + ci)) << 18) + ((size_t)(iy & 511) << 9);
    float* dst = &xt[rIdx*516];
    float4 v = make_float4(0.f, 0.f, 0.f, 0.f);
    if (yok) v = *(const float4*)&xr[c4];
    dst[c4 + 1] = v.x; dst[c4 + 2] = v.y; dst[c4 + 3] = v.z; dst[c4 + 4] = v.w;
    if (l128 == 0){ dst[0] = 0.f; dst[513] = 0.f; }
  }
  __syncthreads();
  const int w = t >> 6, l = t & 63;
  const int oyr = w & 1, xh = w >> 1;
  float acc[2][16];
#pragma unroll
  for (int j = 0; j < 2; j++)
#pragma unroll
    for (int q = 0; q < 16; q++) acc[j][q] = 0.f;

  for (int ci = 0; ci < 3; ci++){
    for (int ky = 0; ky < 4; ky++){
      const float* xrow = &xt[(ci*6 + (oyr << 1) + ky)*516];
      float v[2][4];
#pragma unroll
      for (int j = 0; j < 2; j++){
        int ox = (xh << 7) + (j << 6) + l;
        float2 p0 = *(const float2*)&xrow[2*ox];
        float2 p1 = *(const float2*)&xrow[2*ox + 2];
        v[j][0] = p0.x; v[j][1] = p0.y; v[j][2] = p1.x; v[j][3] = p1.y;
      }
      const float* wb = &wt1[((ci*4 + ky) << 6)];
#pragma unroll
      for (int kx = 0; kx < 4; kx++){
        const float* wp = wb + (kx << 4);        // uniform -> s_load
        float wv[16];
#pragma unroll
        for (int q = 0; q < 16; q++) wv[q] = wp[q];
#pragma unroll
        for (int j = 0; j < 2; j++)
#pragma unroll
          for (int q = 0; q < 16; q++) acc[j][q] = fmaf(v[j][kx], wv[q], acc[j][q]);
      }
    }
  }
  float s[16], ss[16];
#pragma unroll
  for (int q = 0; q < 16; q++){ s[q] = 0.f; ss[q] = 0.f; }
  const int xp = l & 1;
#pragma unroll
  for (int j = 0; j < 2; j++){
    int m = (xh << 6) + (j << 5) + (l >> 1);
#pragma unroll
    for (int q = 0; q < 16; q++){
      float vv = acc[j][q];
      h1p[((((size_t)(n*16 + q) << 1) + oyr) << 15) + ((size_t)xp << 14) + (yt << 7) + m] = vv;
      s[q] += vv; ss[q] += vv*vv;
    }
  }
#pragma unroll
  for (int q = 0; q < 16; q++){ s[q] = wredf(s[q]); ss[q] = wredf(ss[q]); }
  if (l == 0){
#pragma unroll
    for (int q = 0; q < 16; q++){ red[w*32 + q] = s[q]; red[w*32 + 16 + q] = ss[q]; }
  }
  __syncthreads();
  if (t < 32) part1[b*32 + t] = red[t] + red[32+t] + red[64+t] + red[96+t];
}

// ---------------- reduce partials -> scale/shift (BN) ------------------------
__global__ __launch_bounds__(256) void k_stats(
    const float* __restrict__ part, int nslots, int slotstride, int grouped,
    const float* __restrict__ g, const float* __restrict__ be,
    float* __restrict__ scale, float* __restrict__ shift, float Ninv)
{
  const int c = blockIdx.x, t = threadIdx.x;
  const int off = grouped ? ((c >> 4) << 5) : 0;
  const int ci = grouped ? (c & 15) : c;
  float S = 0.f, SS = 0.f;
  for (int q = t; q < nslots; q += 256){
    const float* pp = &part[(size_t)q * slotstride + off];
    S += pp[ci]; SS += pp[16 + ci];
  }
  S = wredf(S); SS = wredf(SS);
  __shared__ float sb[8];
  if ((t & 63) == 0){ sb[t >> 6] = S; sb[4 + (t >> 6)] = SS; }
  __syncthreads();
  if (t == 0){
    float Sv = sb[0]+sb[1]+sb[2]+sb[3], SSv = sb[4]+sb[5]+sb[6]+sb[7];
    float m = Sv * Ninv;
    float var = SSv * Ninv - m*m;
    float sc = g[c] * rsqrtf(var + EPSB);
    scale[c] = sc;
    shift[c] = be[c] - m * sc;
  }
}

// ---------------- k3: conv2 16->64 s2 p1 — direct-L1, zero staging ----------
__global__ __launch_bounds__(256) void k3_conv2(
    const float* __restrict__ h1p, const float* __restrict__ wt2,
    const float* __restrict__ misc, float* __restrict__ h2,
    float* __restrict__ part2)
{
  __shared__ float red[128];
  const int b = blockIdx.x, t = threadIdx.x;
  const int n = b >> 6, yt = b & 63;
  const int oy0 = yt << 1;
  const int w = __builtin_amdgcn_readfirstlane(t >> 6);  // co-group
  const int l = t & 63, oyr = l >> 5, lx = l & 31;
  float acc[4][16];
#pragma unroll
  for (int e = 0; e < 4; e++)
#pragma unroll
    for (int q = 0; q < 16; q++) acc[e][q] = 0.f;

  const int myk[4] = {oy0 + oyr - 1, oy0 + oyr, oy0 + oyr, oy0 + oyr + 1};
  const int ypk[4] = {1, 0, 1, 0};
  const int lxo = lx << 2;

#pragma unroll 2
  for (int g = 0; g < 16; g++){
    const float sc = misc[g], sh = misc[16 + g];         // uniform -> s_load
    const float* pg = h1p + (((size_t)(n*16 + g)) << 16);
#pragma unroll
    for (int ky = 0; ky < 4; ky++){
      const int m_y = myk[ky];
      const bool rv = (unsigned)m_y < 128u;
      const int myc = m_y & 127;
      const float scv = rv ? sc : 0.f, shv = rv ? sh : 0.f;
      const float* rb = pg + ((size_t)ypk[ky] << 15) + (myc << 7) + lxo;
      float4 R0 = *(const float4*)rb;              // xp0 m..m+3
      float4 R1 = *(const float4*)(rb + 16384);    // xp1 m..m+3
      float A0x = fmaxf(fmaf(R0.x, scv, shv), 0.f);
      float A0y = fmaxf(fmaf(R0.y, scv, shv), 0.f);
      float A0z = fmaxf(fmaf(R0.z, scv, shv), 0.f);
      float A0w = fmaxf(fmaf(R0.w, scv, shv), 0.f);
      float A1x = fmaxf(fmaf(R1.x, scv, shv), 0.f);
      float A1y = fmaxf(fmaf(R1.y, scv, shv), 0.f);
      float A1z = fmaxf(fmaf(R1.z, scv, shv), 0.f);
      float A1w = fmaxf(fmaf(R1.w, scv, shv), 0.f);
      float nx0 = __shfl_down(A0x, 1, 64);  if (lx == 31) nx0 = 0.f;
      float pv1 = __shfl_up(A1w, 1, 64);    if (lx == 0)  pv1 = 0.f;
      float act0[4] = {pv1, A1x, A1y, A1z};   // kx=0: xp1 m-1
      float act1[4] = {A0x, A0y, A0z, A0w};   // kx=1: xp0 m
      float act2[4] = {A1x, A1y, A1z, A1w};   // kx=2: xp1 m
      float act3[4] = {A0y, A0z, A0w, nx0};   // kx=3: xp0 m+1
      const float* wb = &wt2[(((g << 4) + (ky << 2)) << 6) + (w << 4)];
#pragma unroll
      for (int kx = 0; kx < 4; kx++){
        const float* wp = wb + (kx << 6);      // uniform -> s_load x16
        float wv[16];
#pragma unroll
        for (int q = 0; q < 16; q++) wv[q] = wp[q];
        const float* av = (kx == 0) ? act0 : (kx == 1) ? act1 : (kx == 2) ? act2 : act3;
#pragma unroll
        for (int e = 0; e < 4; e++)
#pragma unroll
          for (int q = 0; q < 16; q++)
            acc[e][q] = fmaf(av[e], wv[q], acc[e][q]);
      }
    }
  }
  const int oy = oy0 + oyr;
  float s[16], ss[16];
#pragma unroll
  for (int q = 0; q < 16; q++){ s[q] = 0.f; ss[q] = 0.f; }
#pragma unroll
  for (int e = 0; e < 4; e++)
#pragma unroll
    for (int q = 0; q < 16; q++){ float v = acc[e][q]; s[q] += v; ss[q] += v*v; }
#pragma unroll
  for (int q = 0; q < 16; q++){
    float4 o = make_float4(acc[0][q], acc[1][q], acc[2][q], acc[3][q]);
    *(float4*)&h2[(((size_t)(n*64) + (w << 4) + q) << 14) + (oy << 7) + (lx << 2)] = o;
  }
#pragma unroll
  for (int q = 0; q < 16; q++){ s[q] = wredf(s[q]); ss[q] = wredf(ss[q]); }
  if (l == 0){
#pragma unroll
    for (int q = 0; q < 16; q++){ red[w*32 + q] = s[q]; red[w*32 + 16 + q] = ss[q]; }
  }
  __syncthreads();
  if (t < 128) part2[b*128 + t] = red[t];
}

// ---------------- k5: preq(bn2+relu fused) + VQ argmin + qloss + idx ---------
__global__ __launch_bounds__(256) void k5_vq(
    const float* __restrict__ h2, const float* __restrict__ misc,
    const float* __restrict__ pw, const float* __restrict__ pb,
    const float* __restrict__ emb, unsigned char* __restrict__ idxb,
    float* __restrict__ qsum)
{
  __shared__ float eb[4];
  const int t = threadIdx.x;
  const int p0 = blockIdx.x*512 + (t << 1);
  const int n = p0 >> 14, pos = p0 & 16383;
  const float* hp = h2 + ((size_t)n << 20) + pos;
  float q0[2], q1[2];
  const float pb0 = pb[0], pb1 = pb[1];
#pragma unroll
  for (int j = 0; j < 2; j++){ q0[j] = pb0; q1[j] = pb1; }
  for (int c = 0; c < 64; c++){
    float2 v = *(const float2*)&hp[(size_t)c << 14];
    float sc = misc[32 + c], sh = misc[96 + c];   // uniform -> s_load
    float w0 = pw[c], w1 = pw[64 + c];            // uniform -> s_load
    float a0 = fmaxf(fmaf(v.x, sc, sh), 0.f);
    float a1 = fmaxf(fmaf(v.y, sc, sh), 0.f);
    q0[0] = fmaf(a0, w0, q0[0]); q1[0] = fmaf(a0, w1, q1[0]);
    q0[1] = fmaf(a1, w0, q0[1]); q1[1] = fmaf(a1, w1, q1[1]);
  }
  const float e00 = emb[0], e01 = emb[1], e10 = emb[2], e11 = emb[3],
              e20 = emb[4], e21 = emb[5];
  float esum = 0.f;
  unsigned char bi[2];
#pragma unroll
  for (int j = 0; j < 2; j++){
    float dx0 = q0[j]-e00, dy0 = q1[j]-e01;
    float dx1 = q0[j]-e10, dy1 = q1[j]-e11;
    float dx2 = q0[j]-e20, dy2 = q1[j]-e21;
    float d0 = dx0*dx0+dy0*dy0, d1 = dx1*dx1+dy1*dy1, d2 = dx2*dx2+dy2*dy2;
    int bj = 0; float db = d0;
    if (d1 < db){ db = d1; bj = 1; }
    if (d2 < db){ db = d2; bj = 2; }
    bi[j] = (unsigned char)bj; esum += db;
  }
  *(uchar2*)&idxb[p0] = make_uchar2(bi[0], bi[1]);
  float e = wredf(esum);
  if ((t & 63) == 0) eb[t >> 6] = e;
  __syncthreads();
  if (t == 0) atomicAdd(qsum, eb[0]+eb[1]+eb[2]+eb[3]);
}

// d1raw at (iy,ix): sum of <=4 TT entries via idx map (convT1 collapsed).
__device__ __forceinline__ void d1_accum(const unsigned char* __restrict__ ib,
    int iy, int ix, const float* __restrict__ tt, float* __restrict__ d)
{
  const int py = (iy + 1) & 1, px = (ix + 1) & 1;
#pragma unroll
  for (int kyi = 0; kyi < 2; kyi++){
    int ky = py + 2*kyi, jy = (iy + 1 - ky) >> 1;
    if ((unsigned)jy < 128u){
#pragma unroll
      for (int kxi = 0; kxi < 2; kxi++){
        int kx = px + 2*kxi, jx = (ix + 1 - kx) >> 1;
        if ((unsigned)jx < 128u){
          const float4* tb = (const float4*)&tt[(int)ib[(jy << 7) + jx]*260
                                                + (((ky << 2) + kx) << 4)];
          float4 t0 = tb[0], t1 = tb[1], t2 = tb[2], t3 = tb[3];
          d[0]  += t0.x; d[1]  += t0.y; d[2]  += t0.z; d[3]  += t0.w;
          d[4]  += t1.x; d[5]  += t1.y; d[6]  += t1.z; d[7]  += t1.w;
          d[8]  += t2.x; d[9]  += t2.y; d[10] += t2.z; d[11] += t2.w;
          d[12] += t3.x; d[13] += t3.y; d[14] += t3.z; d[15] += t3.w;
        }
      }
    }
  }
}

// ---------------- k7s: d1 stats (fp32) + materialize fp16 channel-last ------
// d1h[p*16 + q], p = (n<<16)+(iy<<8)+ix -> write addr = p*32B, contiguous.
__global__ __launch_bounds__(256) void k7s(
    const unsigned char* __restrict__ idxb, const float* __restrict__ misc,
    __half* __restrict__ d1h, float* __restrict__ partd, float* __restrict__ qout)
{
  __shared__ __align__(16) float tt[780];
  __shared__ float red[128];
  const int b = blockIdx.x, t = threadIdx.x;
  for (int s = t; s < 780; s += 256) tt[s] = misc[400 + s];
  __syncthreads();
  if (b == 0 && t == 0) qout[0] = 1.2f * misc[192] * (1.0f/1048576.0f);
  float s[16], ss[16];
#pragma unroll
  for (int q = 0; q < 16; q++){ s[q] = 0.f; ss[q] = 0.f; }
  for (int k = 0; k < 4; k++){
    int p = (b << 10) + (k << 8) + t;
    int n = p >> 16, rem = p & 65535, iy = rem >> 8, ix = rem & 255;
    const unsigned char* ib = idxb + ((size_t)n << 14);
    float d[16];
#pragma unroll
    for (int q = 0; q < 16; q++) d[q] = 0.f;
    d1_accum(ib, iy, ix, tt, d);
    union { __half2 h[8]; uint4 u[2]; } pk;
#pragma unroll
    for (int j = 0; j < 8; j++) pk.h[j] = __floats2half2_rn(d[2*j], d[2*j + 1]);
    uint4* dp = (uint4*)(d1h + ((size_t)p << 4));
    dp[0] = pk.u[0]; dp[1] = pk.u[1];
#pragma unroll
    for (int q = 0; q < 16; q++){ s[q] += d[q]; ss[q] += d[q]*d[q]; }
  }
#pragma unroll
  for (int q = 0; q < 16; q++){ s[q] = wredf(s[q]); ss[q] = wredf(ss[q]); }
  const int w = t >> 6, l = t & 63;
  if (l == 0){
#pragma unroll
    for (int q = 0; q < 16; q++){ red[w*32 + q] = s[q]; red[w*32 + 16 + q] = ss[q]; }
  }
  __syncthreads();
  if (t < 32) partd[b*32 + t] = red[t] + red[32+t] + red[64+t] + red[96+t];
}

// ---------------- k9: convT2 streaming from fp16 channel-last d1 + tanh -----
// Block = one out row (n, oy); thread m handles out cols 2m, 2m+1, all 3 co.
__global__ __launch_bounds__(256) void k9_dec(
    const __half* __restrict__ d1h, const float* __restrict__ misc,
    const float* __restrict__ wt9b, const float* __restrict__ db2,
    float* __restrict__ out)
{
  const int b = blockIdx.x, m = threadIdx.x;
  const int n = b >> 9, oy = b & 511;
  const int py = (oy + 1) & 1;
  float accA[3] = {0.f, 0.f, 0.f};   // out col 2m
  float accB[3] = {0.f, 0.f, 0.f};   // out col 2m+1
#pragma unroll
  for (int kyi = 0; kyi < 2; kyi++){
    const int ky = py + (kyi << 1);
    const int iy = (oy + 1 - ky) >> 1;
    if ((unsigned)iy < 256u){                     // wave-uniform
      const __half* rbp = d1h + (((size_t)((n << 16) + (iy << 8))) << 4);
      float a[16];
      d1_act_h(rbp + ((size_t)m << 4), misc, a);  // ix = m
      wacc(a, &wt9b[(((ky << 2) + 1) << 4)*3], accA);   // kx=1 -> col 2m
      wacc(a, &wt9b[(((ky << 2) + 2) << 4)*3], accB);   // kx=2 -> col 2m+1
      if (m > 0){                                 // ix = m-1, kx=3 -> col 2m
        d1_act_h(rbp + ((size_t)(m - 1) << 4), misc, a);
        wacc(a, &wt9b[(((ky << 2) + 3) << 4)*3], accA);
      }
      if (m < 255){                               // ix = m+1, kx=0 -> col 2m+1
        d1_act_h(rbp + ((size_t)(m + 1) << 4), misc, a);
        wacc(a, &wt9b[(((ky << 2) + 0) << 4)*3], accB);
      }
    }
  }
#pragma unroll
  for (int co = 0; co < 3; co++){
    const float bb = db2[co];
    float2 o = make_float2(fast_tanh(accA[co] + bb), fast_tanh(accB[co] + bb));
    *(float2*)&out[((size_t)(n*3 + co) << 18) + ((size_t)oy << 9) + (m << 1)] = o;
  }
}

// ---------------------------------------------------------------------------
extern "C" void kernel_launch(void* const* d_in, const int* in_sizes, int n_in,
                              void* d_out, int out_size, void* d_ws, size_t ws_size,
                              hipStream_t stream)
{
  (void)in_sizes; (void)n_in; (void)out_size;
  const float* x       = (const float*)d_in[0];
  const float* enc_w1  = (const float*)d_in[1];
  const float* enc_g1  = (const float*)d_in[3];
  const float* enc_be1 = (const float*)d_in[4];
  const float* enc_w2  = (const float*)d_in[5];
  const float* enc_g2  = (const float*)d_in[7];
  const float* enc_be2 = (const float*)d_in[8];
  const float* preq_w  = (const float*)d_in[9];
  const float* preq_b  = (const float*)d_in[10];
  const float* emb     = (const float*)d_in[11];
  const float* postq_w = (const float*)d_in[12];
  const float* postq_b = (const float*)d_in[13];
  const float* dec_w1  = (const float*)d_in[14];
  const float* dec_g1  = (const float*)d_in[16];
  const float* dec_be1 = (const float*)d_in[17];
  const float* dec_w2  = (const float*)d_in[18];
  const float* dec_b2  = (const float*)d_in[19];
  float* out = (float*)d_out;
  char*  ws  = (char*)d_ws;

  float* h1p = (float*)ws;                         // 134217728 B (later d1h)
  float* h2  = (float*)(ws + 134217728);           // 134217728 B
  size_t ebase = (ws_size - 4194304) & ~(size_t)255;
  unsigned char* idxb = (unsigned char*)(ws + ebase);            // 512 KB
  float* part1 = (float*)(ws + ebase + 524288);                  // 512 KB
  float* partd = (float*)(ws + ebase + 1048576);                 // 256 KB
  float* misc  = (float*)(ws + ebase + 1310720);                 // 8 KB
  float* wt1   = (float*)(ws + ebase + 1318912);                 // 3 KB
  float* wt2   = (float*)(ws + ebase + 1327104);                 // 64 KB
  float* wt9   = (float*)(ws + ebase + 1392640);                 // 3 KB
  float* part2 = out;     // 4 MB, overwritten by k9's recon afterwards
  __half* d1h  = (__half*)h1p;   // h1p dead after k3 -> reuse (64 MiB used)

  kP<<<64, 256, 0, stream>>>(enc_w1, enc_w2, dec_w2,
                             postq_w, postq_b, emb, wt1, wt2, wt9, misc);
  k6b_tt<<<768, 64, 0, stream>>>(dec_w1, misc);
  k1_conv1<<<4096, 256, 0, stream>>>(x, wt1, h1p, part1);
  k_stats<<<16, 256, 0, stream>>>(part1, 4096, 32, 0, enc_g1, enc_be1,
                                  misc + 0, misc + 16, 1.f/2097152.f);
  k3_conv2<<<2048, 256, 0, stream>>>(h1p, wt2, misc, h2, part2);
  k_stats<<<64, 256, 0, stream>>>(part2, 2048, 128, 1, enc_g2, enc_be2,
                                  misc + 32, misc + 96, 1.f/524288.f);
  k5_vq<<<1024, 256, 0, stream>>>(h2, misc, preq_w, preq_b, emb, idxb, misc + 192);
  k7s<<<2048, 256, 0, stream>>>(idxb, misc, d1h, partd, out + 25165824);
  k_stats<<<16, 256, 0, stream>>>(partd, 2048, 32, 0, dec_g1, dec_be1,
                                  misc + 160, misc + 176, 1.f/2097152.f);
  k9_dec<<<16384, 256, 0, stream>>>(d1h, misc, wt9, dec_b2, out);
}

// Round 18
// 432.897 us; speedup vs baseline: 1.8342x; 1.0519x over previous
//
#include <hip/hip_runtime.h>
#include <hip/hip_bf16.h>
#include <hip/hip_fp16.h>

// VQVAE forward, MI355X, fp32 encoder path (argmin stability).
// v18 = v17 with (a) k3 reverted to the v16 g-loop (unroll-2 cost a wave of
// occupancy: 195->217us); (b) k5 widened to float4/4px per thread (same
// per-pixel fmaf chain -> idx bit-identical). fp16 d1 decoder kept.
// enc_b1/enc_b2/dec_b1 cancelled by training-mode BN -> unused.

#define EPSB 1e-5f

__device__ __forceinline__ float wredf(float v){
#pragma unroll
  for (int m = 32; m >= 1; m >>= 1) v += __shfl_xor(v, m, 64);
  return v;
}

__device__ __forceinline__ float fast_tanh(float x){
  float e = __expf(2.f * x);
  return fmaf(-2.f, __builtin_amdgcn_rcpf(e + 1.f), 1.f);
}

// act[16] = relu(bn(fp16 d1 pixel)) ; all static indices
__device__ __forceinline__ void d1_act_h(const __half* __restrict__ p,
    const float* __restrict__ misc, float* __restrict__ a){
  union { uint4 u[2]; __half2 h[8]; } pk;
  const uint4* U = (const uint4*)p;
  pk.u[0] = U[0]; pk.u[1] = U[1];
#pragma unroll
  for (int j = 0; j < 8; j++){
    float2 f = __half22float2(pk.h[j]);
    a[2*j]     = fmaxf(fmaf(f.x, misc[160 + 2*j],     misc[176 + 2*j]),     0.f);
    a[2*j + 1] = fmaxf(fmaf(f.y, misc[160 + 2*j + 1], misc[176 + 2*j + 1]), 0.f);
  }
}

// acc[0..2] += sum_ci a[ci] * wp[ci*3+co]   (wp uniform -> s_load)
__device__ __forceinline__ void wacc(const float* __restrict__ a,
    const float* __restrict__ wp, float* __restrict__ acc){
#pragma unroll
  for (int ci = 0; ci < 16; ci++){
    acc[0] = fmaf(a[ci], wp[ci*3 + 0], acc[0]);
    acc[1] = fmaf(a[ci], wp[ci*3 + 1], acc[1]);
    acc[2] = fmaf(a[ci], wp[ci*3 + 2], acc[2]);
  }
}

// ---------------- kP: weight transposes + P table + qsum=0 ------------------
__global__ __launch_bounds__(256) void kP(
    const float* __restrict__ w1, const float* __restrict__ w2,
    const float* __restrict__ dw2,
    const float* __restrict__ pqw, const float* __restrict__ pqb,
    const float* __restrict__ emb,
    float* __restrict__ wt1, float* __restrict__ wt2,
    float* __restrict__ wt9, float* __restrict__ misc)
{
  const int b = blockIdx.x, t = threadIdx.x;
  const int s = b*256 + t;                       // 0..16383
  { int tap = s >> 6, co = s & 63;               // wt2[tap=ci*16+ky*4+kx][co64]
    int ci = tap >> 4, ky = (tap >> 2) & 3, kx = tap & 3;
    wt2[s] = w2[((co*16 + ci)*4 + ky)*4 + kx]; }
  if (b == 0){
    for (int s2 = t; s2 < 768; s2 += 256){
      int tap = s2 >> 4, co = s2 & 15;           // wt1[tap][co16]
      int ci = tap >> 4, ky = (tap >> 2) & 3, kx = tap & 3;
      wt1[s2] = w1[((co*3 + ci)*4 + ky)*4 + kx];
      // wt9b[((ky*4+kx)*16+ci)*3+co] = dec_w2[ci][co][ky][kx]
      int co9 = s2 % 3, r3 = s2 / 3;
      int ci9 = r3 & 15, kykx = r3 >> 4;
      int ky9 = kykx >> 2, kx9 = kykx & 3;
      wt9[s2] = dw2[((ci9*3 + co9)*4 + ky9)*4 + kx9];
    }
    if (t < 192){                                // P[i][ci] = postq(emb[i])
      int i = t >> 6, ci = t & 63;
      misc[200 + t] = fmaf(pqw[ci*2], emb[i*2],
                      fmaf(pqw[ci*2 + 1], emb[i*2 + 1], pqb[ci]));
    }
    if (t == 255) misc[192] = 0.f;               // qloss accumulator
  }
}

// ---------------- k6b: TT[i][ky][kx][oc] = sum_ci dec_w1 * P (parallel) -----
__global__ __launch_bounds__(64) void k6b_tt(
    const float* __restrict__ dw1, float* __restrict__ misc)
{
  const int e = blockIdx.x;                 // i*256 + (ky*4+kx)*16 + oc
  const int i = e >> 8, rem = e & 255;
  const int kykx = rem >> 4, oc = rem & 15;
  const int ky = kykx >> 2, kx = kykx & 3;
  const int l = threadIdx.x;                // ci (0..63)
  float v = dw1[((l*16 + oc)*4 + ky)*4 + kx] * misc[200 + i*64 + l];
  v = wredf(v);
  if (l == 0) misc[400 + i*260 + rem] = v;  // stride 260 pad (1040B, 16B-mult)
}

// ---------------- k1: conv1 3->16 s2 p1 -> parity-split h1p + stats ----------
// h1p[n][co16][yp][xp][128][128]; yp=oy&1, xp=ox&1.
__global__ __launch_bounds__(256) void k1_conv1(
    const float* __restrict__ x, const float* __restrict__ wt1,
    float* __restrict__ h1p, float* __restrict__ part1)
{
  __shared__ __align__(16) float xt[3*6*516];
  __shared__ float red[128];
  const int b = blockIdx.x, t = threadIdx.x;
  const int n = b >> 7, yt = b & 127;
  const int oy0 = yt << 1, iy0 = (oy0 << 1) - 1;
  const int rh = t >> 7, l128 = t & 127, c4 = l128 << 2;
#pragma unroll
  for (int rp = 0; rp < 9; rp++){
    int rIdx = (rp << 1) + rh;              // 0..17 = ci*6+rr
    int ci = rIdx / 6, rr = rIdx - ci*6;
    int iy = iy0 + rr;
    bool yok = (unsigned)iy < 512u;
    const float* xr = x + (((size_t)(n*3 + ci)) << 18) + ((size_t)(iy & 511) << 9);
    float* dst = &xt[rIdx*516];
    float4 v = make_float4(0.f, 0.f, 0.f, 0.f);
    if (yok) v = *(const float4*)&xr[c4];
    dst[c4 + 1] = v.x; dst[c4 + 2] = v.y; dst[c4 + 3] = v.z; dst[c4 + 4] = v.w;
    if (l128 == 0){ dst[0] = 0.f; dst[513] = 0.f; }
  }
  __syncthreads();
  const int w = t >> 6, l = t & 63;
  const int oyr = w & 1, xh = w >> 1;
  float acc[2][16];
#pragma unroll
  for (int j = 0; j < 2; j++)
#pragma unroll
    for (int q = 0; q < 16; q++) acc[j][q] = 0.f;

  for (int ci = 0; ci < 3; ci++){
    for (int ky = 0; ky < 4; ky++){
      const float* xrow = &xt[(ci*6 + (oyr << 1) + ky)*516];
      float v[2][4];
#pragma unroll
      for (int j = 0; j < 2; j++){
        int ox = (xh << 7) + (j << 6) + l;
        float2 p0 = *(const float2*)&xrow[2*ox];
        float2 p1 = *(const float2*)&xrow[2*ox + 2];
        v[j][0] = p0.x; v[j][1] = p0.y; v[j][2] = p1.x; v[j][3] = p1.y;
      }
      const float* wb = &wt1[((ci*4 + ky) << 6)];
#pragma unroll
      for (int kx = 0; kx < 4; kx++){
        const float* wp = wb + (kx << 4);        // uniform -> s_load
        float wv[16];
#pragma unroll
        for (int q = 0; q < 16; q++) wv[q] = wp[q];
#pragma unroll
        for (int j = 0; j < 2; j++)
#pragma unroll
          for (int q = 0; q < 16; q++) acc[j][q] = fmaf(v[j][kx], wv[q], acc[j][q]);
      }
    }
  }
  float s[16], ss[16];
#pragma unroll
  for (int q = 0; q < 16; q++){ s[q] = 0.f; ss[q] = 0.f; }
  const int xp = l & 1;
#pragma unroll
  for (int j = 0; j < 2; j++){
    int m = (xh << 6) + (j << 5) + (l >> 1);
#pragma unroll
    for (int q = 0; q < 16; q++){
      float vv = acc[j][q];
      h1p[((((size_t)(n*16 + q) << 1) + oyr) << 15) + ((size_t)xp << 14) + (yt << 7) + m] = vv;
      s[q] += vv; ss[q] += vv*vv;
    }
  }
#pragma unroll
  for (int q = 0; q < 16; q++){ s[q] = wredf(s[q]); ss[q] = wredf(ss[q]); }
  if (l == 0){
#pragma unroll
    for (int q = 0; q < 16; q++){ red[w*32 + q] = s[q]; red[w*32 + 16 + q] = ss[q]; }
  }
  __syncthreads();
  if (t < 32) part1[b*32 + t] = red[t] + red[32+t] + red[64+t] + red[96+t];
}

// ---------------- reduce partials -> scale/shift (BN) ------------------------
__global__ __launch_bounds__(256) void k_stats(
    const float* __restrict__ part, int nslots, int slotstride, int grouped,
    const float* __restrict__ g, const float* __restrict__ be,
    float* __restrict__ scale, float* __restrict__ shift, float Ninv)
{
  const int c = blockIdx.x, t = threadIdx.x;
  const int off = grouped ? ((c >> 4) << 5) : 0;
  const int ci = grouped ? (c & 15) : c;
  float S = 0.f, SS = 0.f;
  for (int q = t; q < nslots; q += 256){
    const float* pp = &part[(size_t)q * slotstride + off];
    S += pp[ci]; SS += pp[16 + ci];
  }
  S = wredf(S); SS = wredf(SS);
  __shared__ float sb[8];
  if ((t & 63) == 0){ sb[t >> 6] = S; sb[4 + (t >> 6)] = SS; }
  __syncthreads();
  if (t == 0){
    float Sv = sb[0]+sb[1]+sb[2]+sb[3], SSv = sb[4]+sb[5]+sb[6]+sb[7];
    float m = Sv * Ninv;
    float var = SSv * Ninv - m*m;
    float sc = g[c] * rsqrtf(var + EPSB);
    scale[c] = sc;
    shift[c] = be[c] - m * sc;
  }
}

// ---------------- k3: conv2 16->64 s2 p1 — direct-L1, zero staging ----------
__global__ __launch_bounds__(256) void k3_conv2(
    const float* __restrict__ h1p, const float* __restrict__ wt2,
    const float* __restrict__ misc, float* __restrict__ h2,
    float* __restrict__ part2)
{
  __shared__ float red[128];
  const int b = blockIdx.x, t = threadIdx.x;
  const int n = b >> 6, yt = b & 63;
  const int oy0 = yt << 1;
  const int w = __builtin_amdgcn_readfirstlane(t >> 6);  // co-group
  const int l = t & 63, oyr = l >> 5, lx = l & 31;
  float acc[4][16];
#pragma unroll
  for (int e = 0; e < 4; e++)
#pragma unroll
    for (int q = 0; q < 16; q++) acc[e][q] = 0.f;

  const int myk[4] = {oy0 + oyr - 1, oy0 + oyr, oy0 + oyr, oy0 + oyr + 1};
  const int ypk[4] = {1, 0, 1, 0};
  const int lxo = lx << 2;

  for (int g = 0; g < 16; g++){
    const float sc = misc[g], sh = misc[16 + g];         // uniform -> s_load
    const float* pg = h1p + (((size_t)(n*16 + g)) << 16);
#pragma unroll
    for (int ky = 0; ky < 4; ky++){
      const int m_y = myk[ky];
      const bool rv = (unsigned)m_y < 128u;
      const int myc = m_y & 127;
      const float scv = rv ? sc : 0.f, shv = rv ? sh : 0.f;
      const float* rb = pg + ((size_t)ypk[ky] << 15) + (myc << 7) + lxo;
      float4 R0 = *(const float4*)rb;              // xp0 m..m+3
      float4 R1 = *(const float4*)(rb + 16384);    // xp1 m..m+3
      float A0x = fmaxf(fmaf(R0.x, scv, shv), 0.f);
      float A0y = fmaxf(fmaf(R0.y, scv, shv), 0.f);
      float A0z = fmaxf(fmaf(R0.z, scv, shv), 0.f);
      float A0w = fmaxf(fmaf(R0.w, scv, shv), 0.f);
      float A1x = fmaxf(fmaf(R1.x, scv, shv), 0.f);
      float A1y = fmaxf(fmaf(R1.y, scv, shv), 0.f);
      float A1z = fmaxf(fmaf(R1.z, scv, shv), 0.f);
      float A1w = fmaxf(fmaf(R1.w, scv, shv), 0.f);
      float nx0 = __shfl_down(A0x, 1, 64);  if (lx == 31) nx0 = 0.f;
      float pv1 = __shfl_up(A1w, 1, 64);    if (lx == 0)  pv1 = 0.f;
      float act0[4] = {pv1, A1x, A1y, A1z};   // kx=0: xp1 m-1
      float act1[4] = {A0x, A0y, A0z, A0w};   // kx=1: xp0 m
      float act2[4] = {A1x, A1y, A1z, A1w};   // kx=2: xp1 m
      float act3[4] = {A0y, A0z, A0w, nx0};   // kx=3: xp0 m+1
      const float* wb = &wt2[(((g << 4) + (ky << 2)) << 6) + (w << 4)];
#pragma unroll
      for (int kx = 0; kx < 4; kx++){
        const float* wp = wb + (kx << 6);      // uniform -> s_load x16
        float wv[16];
#pragma unroll
        for (int q = 0; q < 16; q++) wv[q] = wp[q];
        const float* av = (kx == 0) ? act0 : (kx == 1) ? act1 : (kx == 2) ? act2 : act3;
#pragma unroll
        for (int e = 0; e < 4; e++)
#pragma unroll
          for (int q = 0; q < 16; q++)
            acc[e][q] = fmaf(av[e], wv[q], acc[e][q]);
      }
    }
  }
  const int oy = oy0 + oyr;
  float s[16], ss[16];
#pragma unroll
  for (int q = 0; q < 16; q++){ s[q] = 0.f; ss[q] = 0.f; }
#pragma unroll
  for (int e = 0; e < 4; e++)
#pragma unroll
    for (int q = 0; q < 16; q++){ float v = acc[e][q]; s[q] += v; ss[q] += v*v; }
#pragma unroll
  for (int q = 0; q < 16; q++){
    float4 o = make_float4(acc[0][q], acc[1][q], acc[2][q], acc[3][q]);
    *(float4*)&h2[(((size_t)(n*64) + (w << 4) + q) << 14) + (oy << 7) + (lx << 2)] = o;
  }
#pragma unroll
  for (int q = 0; q < 16; q++){ s[q] = wredf(s[q]); ss[q] = wredf(ss[q]); }
  if (l == 0){
#pragma unroll
    for (int q = 0; q < 16; q++){ red[w*32 + q] = s[q]; red[w*32 + 16 + q] = ss[q]; }
  }
  __syncthreads();
  if (t < 128) part2[b*128 + t] = red[t];
}

// ---------------- k5: preq(bn2+relu fused) + VQ argmin + qloss + idx ---------
// 4 px/thread, float4 loads; coeffs at uniform index -> s_load.
__global__ __launch_bounds__(256) void k5_vq(
    const float* __restrict__ h2, const float* __restrict__ misc,
    const float* __restrict__ pw, const float* __restrict__ pb,
    const float* __restrict__ emb, unsigned char* __restrict__ idxb,
    float* __restrict__ qsum)
{
  __shared__ float eb[4];
  const int t = threadIdx.x;
  const int p0 = blockIdx.x*1024 + (t << 2);
  const int n = p0 >> 14, pos = p0 & 16383;
  const float* hp = h2 + ((size_t)n << 20) + pos;
  float q0[4], q1[4];
  const float pb0 = pb[0], pb1 = pb[1];
#pragma unroll
  for (int j = 0; j < 4; j++){ q0[j] = pb0; q1[j] = pb1; }
  for (int c = 0; c < 64; c++){
    float4 v = *(const float4*)&hp[(size_t)c << 14];
    float sc = misc[32 + c], sh = misc[96 + c];   // uniform -> s_load
    float w0 = pw[c], w1 = pw[64 + c];            // uniform -> s_load
    float a0 = fmaxf(fmaf(v.x, sc, sh), 0.f);
    float a1 = fmaxf(fmaf(v.y, sc, sh), 0.f);
    float a2 = fmaxf(fmaf(v.z, sc, sh), 0.f);
    float a3 = fmaxf(fmaf(v.w, sc, sh), 0.f);
    q0[0] = fmaf(a0, w0, q0[0]); q1[0] = fmaf(a0, w1, q1[0]);
    q0[1] = fmaf(a1, w0, q0[1]); q1[1] = fmaf(a1, w1, q1[1]);
    q0[2] = fmaf(a2, w0, q0[2]); q1[2] = fmaf(a2, w1, q1[2]);
    q0[3] = fmaf(a3, w0, q0[3]); q1[3] = fmaf(a3, w1, q1[3]);
  }
  const float e00 = emb[0], e01 = emb[1], e10 = emb[2], e11 = emb[3],
              e20 = emb[4], e21 = emb[5];
  float esum = 0.f;
  unsigned char bi[4];
#pragma unroll
  for (int j = 0; j < 4; j++){
    float dx0 = q0[j]-e00, dy0 = q1[j]-e01;
    float dx1 = q0[j]-e10, dy1 = q1[j]-e11;
    float dx2 = q0[j]-e20, dy2 = q1[j]-e21;
    float d0 = dx0*dx0+dy0*dy0, d1 = dx1*dx1+dy1*dy1, d2 = dx2*dx2+dy2*dy2;
    int bj = 0; float db = d0;
    if (d1 < db){ db = d1; bj = 1; }
    if (d2 < db){ db = d2; bj = 2; }
    bi[j] = (unsigned char)bj; esum += db;
  }
  *(uchar4*)&idxb[p0] = make_uchar4(bi[0], bi[1], bi[2], bi[3]);
  float e = wredf(esum);
  if ((t & 63) == 0) eb[t >> 6] = e;
  __syncthreads();
  if (t == 0) atomicAdd(qsum, eb[0]+eb[1]+eb[2]+eb[3]);
}

// d1raw at (iy,ix): sum of <=4 TT entries via idx map (convT1 collapsed).
__device__ __forceinline__ void d1_accum(const unsigned char* __restrict__ ib,
    int iy, int ix, const float* __restrict__ tt, float* __restrict__ d)
{
  const int py = (iy + 1) & 1, px = (ix + 1) & 1;
#pragma unroll
  for (int kyi = 0; kyi < 2; kyi++){
    int ky = py + 2*kyi, jy = (iy + 1 - ky) >> 1;
    if ((unsigned)jy < 128u){
#pragma unroll
      for (int kxi = 0; kxi < 2; kxi++){
        int kx = px + 2*kxi, jx = (ix + 1 - kx) >> 1;
        if ((unsigned)jx < 128u){
          const float4* tb = (const float4*)&tt[(int)ib[(jy << 7) + jx]*260
                                                + (((ky << 2) + kx) << 4)];
          float4 t0 = tb[0], t1 = tb[1], t2 = tb[2], t3 = tb[3];
          d[0]  += t0.x; d[1]  += t0.y; d[2]  += t0.z; d[3]  += t0.w;
          d[4]  += t1.x; d[5]  += t1.y; d[6]  += t1.z; d[7]  += t1.w;
          d[8]  += t2.x; d[9]  += t2.y; d[10] += t2.z; d[11] += t2.w;
          d[12] += t3.x; d[13] += t3.y; d[14] += t3.z; d[15] += t3.w;
        }
      }
    }
  }
}

// ---------------- k7s: d1 stats (fp32) + materialize fp16 channel-last ------
__global__ __launch_bounds__(256) void k7s(
    const unsigned char* __restrict__ idxb, const float* __restrict__ misc,
    __half* __restrict__ d1h, float* __restrict__ partd, float* __restrict__ qout)
{
  __shared__ __align__(16) float tt[780];
  __shared__ float red[128];
  const int b = blockIdx.x, t = threadIdx.x;
  for (int s = t; s < 780; s += 256) tt[s] = misc[400 + s];
  __syncthreads();
  if (b == 0 && t == 0) qout[0] = 1.2f * misc[192] * (1.0f/1048576.0f);
  float s[16], ss[16];
#pragma unroll
  for (int q = 0; q < 16; q++){ s[q] = 0.f; ss[q] = 0.f; }
  for (int k = 0; k < 4; k++){
    int p = (b << 10) + (k << 8) + t;
    int n = p >> 16, rem = p & 65535, iy = rem >> 8, ix = rem & 255;
    const unsigned char* ib = idxb + ((size_t)n << 14);
    float d[16];
#pragma unroll
    for (int q = 0; q < 16; q++) d[q] = 0.f;
    d1_accum(ib, iy, ix, tt, d);
    union { __half2 h[8]; uint4 u[2]; } pk;
#pragma unroll
    for (int j = 0; j < 8; j++) pk.h[j] = __floats2half2_rn(d[2*j], d[2*j + 1]);
    uint4* dp = (uint4*)(d1h + ((size_t)p << 4));
    dp[0] = pk.u[0]; dp[1] = pk.u[1];
#pragma unroll
    for (int q = 0; q < 16; q++){ s[q] += d[q]; ss[q] += d[q]*d[q]; }
  }
#pragma unroll
  for (int q = 0; q < 16; q++){ s[q] = wredf(s[q]); ss[q] = wredf(ss[q]); }
  const int w = t >> 6, l = t & 63;
  if (l == 0){
#pragma unroll
    for (int q = 0; q < 16; q++){ red[w*32 + q] = s[q]; red[w*32 + 16 + q] = ss[q]; }
  }
  __syncthreads();
  if (t < 32) partd[b*32 + t] = red[t] + red[32+t] + red[64+t] + red[96+t];
}

// ---------------- k9: convT2 streaming from fp16 channel-last d1 + tanh -----
__global__ __launch_bounds__(256) void k9_dec(
    const __half* __restrict__ d1h, const float* __restrict__ misc,
    const float* __restrict__ wt9b, const float* __restrict__ db2,
    float* __restrict__ out)
{
  const int b = blockIdx.x, m = threadIdx.x;
  const int n = b >> 9, oy = b & 511;
  const int py = (oy + 1) & 1;
  float accA[3] = {0.f, 0.f, 0.f};   // out col 2m
  float accB[3] = {0.f, 0.f, 0.f};   // out col 2m+1
#pragma unroll
  for (int kyi = 0; kyi < 2; kyi++){
    const int ky = py + (kyi << 1);
    const int iy = (oy + 1 - ky) >> 1;
    if ((unsigned)iy < 256u){                     // wave-uniform
      const __half* rbp = d1h + (((size_t)((n << 16) + (iy << 8))) << 4);
      float a[16];
      d1_act_h(rbp + ((size_t)m << 4), misc, a);  // ix = m
      wacc(a, &wt9b[(((ky << 2) + 1) << 4)*3], accA);   // kx=1 -> col 2m
      wacc(a, &wt9b[(((ky << 2) + 2) << 4)*3], accB);   // kx=2 -> col 2m+1
      if (m > 0){                                 // ix = m-1, kx=3 -> col 2m
        d1_act_h(rbp + ((size_t)(m - 1) << 4), misc, a);
        wacc(a, &wt9b[(((ky << 2) + 3) << 4)*3], accA);
      }
      if (m < 255){                               // ix = m+1, kx=0 -> col 2m+1
        d1_act_h(rbp + ((size_t)(m + 1) << 4), misc, a);
        wacc(a, &wt9b[(((ky << 2) + 0) << 4)*3], accB);
      }
    }
  }
#pragma unroll
  for (int co = 0; co < 3; co++){
    const float bb = db2[co];
    float2 o = make_float2(fast_tanh(accA[co] + bb), fast_tanh(accB[co] + bb));
    *(float2*)&out[((size_t)(n*3 + co) << 18) + ((size_t)oy << 9) + (m << 1)] = o;
  }
}

// ---------------------------------------------------------------------------
extern "C" void kernel_launch(void* const* d_in, const int* in_sizes, int n_in,
                              void* d_out, int out_size, void* d_ws, size_t ws_size,
                              hipStream_t stream)
{
  (void)in_sizes; (void)n_in; (void)out_size;
  const float* x       = (const float*)d_in[0];
  const float* enc_w1  = (const float*)d_in[1];
  const float* enc_g1  = (const float*)d_in[3];
  const float* enc_be1 = (const float*)d_in[4];
  const float* enc_w2  = (const float*)d_in[5];
  const float* enc_g2  = (const float*)d_in[7];
  const float* enc_be2 = (const float*)d_in[8];
  const float* preq_w  = (const float*)d_in[9];
  const float* preq_b  = (const float*)d_in[10];
  const float* emb     = (const float*)d_in[11];
  const float* postq_w = (const float*)d_in[12];
  const float* postq_b = (const float*)d_in[13];
  const float* dec_w1  = (const float*)d_in[14];
  const float* dec_g1  = (const float*)d_in[16];
  const float* dec_be1 = (const float*)d_in[17];
  const float* dec_w2  = (const float*)d_in[18];
  const float* dec_b2  = (const float*)d_in[19];
  float* out = (float*)d_out;
  char*  ws  = (char*)d_ws;

  float* h1p = (float*)ws;                         // 134217728 B (later d1h)
  float* h2  = (float*)(ws + 134217728);           // 134217728 B
  size_t ebase = (ws_size - 4194304) & ~(size_t)255;
  unsigned char* idxb = (unsigned char*)(ws + ebase);            // 512 KB
  float* part1 = (float*)(ws + ebase + 524288);                  // 512 KB
  float* partd = (float*)(ws + ebase + 1048576);                 // 256 KB
  float* misc  = (float*)(ws + ebase + 1310720);                 // 8 KB
  float* wt1   = (float*)(ws + ebase + 1318912);                 // 3 KB
  float* wt2   = (float*)(ws + ebase + 1327104);                 // 64 KB
  float* wt9   = (float*)(ws + ebase + 1392640);                 // 3 KB
  float* part2 = out;     // 4 MB, overwritten by k9's recon afterwards
  __half* d1h  = (__half*)h1p;   // h1p dead after k3 -> reuse (64 MiB used)

  kP<<<64, 256, 0, stream>>>(enc_w1, enc_w2, dec_w2,
                             postq_w, postq_b, emb, wt1, wt2, wt9, misc);
  k6b_tt<<<768, 64, 0, stream>>>(dec_w1, misc);
  k1_conv1<<<4096, 256, 0, stream>>>(x, wt1, h1p, part1);
  k_stats<<<16, 256, 0, stream>>>(part1, 4096, 32, 0, enc_g1, enc_be1,
                                  misc + 0, misc + 16, 1.f/2097152.f);
  k3_conv2<<<2048, 256, 0, stream>>>(h1p, wt2, misc, h2, part2);
  k_stats<<<64, 256, 0, stream>>>(part2, 2048, 128, 1, enc_g2, enc_be2,
                                  misc + 32, misc + 96, 1.f/524288.f);
  k5_vq<<<512, 256, 0, stream>>>(h2, misc, preq_w, preq_b, emb, idxb, misc + 192);
  k7s<<<2048, 256, 0, stream>>>(idxb, misc, d1h, partd, out + 25165824);
  k_stats<<<16, 256, 0, stream>>>(partd, 2048, 32, 0, dec_g1, dec_be1,
                                  misc + 160, misc + 176, 1.f/2097152.f);
  k9_dec<<<16384, 256, 0, stream>>>(d1h, misc, wt9, dec_b2, out);
}